// Round 1
// 898.546 us; speedup vs baseline: 1.1529x; 1.1529x over previous
//
#include <hip/hip_runtime.h>
#include <cstdint>
#include <cmath>

#define D_DIM   2048
#define S_DIM   1024
#define B_DIM   2
#define H_DIM   16
#define HD_DIM  128
#define MLP_DIM 8192
#define T_DIM   (B_DIM * S_DIM)   // 2048 tokens
#define LDQ     (3 * D_DIM)       // fused QKV row stride (elements)

typedef int      v4i  __attribute__((ext_vector_type(4)));
typedef int      v16i __attribute__((ext_vector_type(16)));
typedef _Float16 v8h  __attribute__((ext_vector_type(8)));
typedef float    v16f __attribute__((ext_vector_type(16)));

__device__ inline void gll16(const void* g, void* l) {
    __builtin_amdgcn_global_load_lds(
        (__attribute__((address_space(1))) void*)g,
        (__attribute__((address_space(3))) void*)l, 16, 0, 0);
}

__device__ inline v16f zero16() {
    v16f z;
    #pragma unroll
    for (int i = 0; i < 16; ++i) z[i] = 0.f;
    return z;
}

// ---------------- block reductions (256 threads) ----------------
__device__ inline float block_reduce_sum_256(float v, float* sm) {
    int tid = threadIdx.x;
    sm[tid] = v; __syncthreads();
    for (int s = 128; s > 0; s >>= 1) {
        if (tid < s) sm[tid] += sm[tid + s];
        __syncthreads();
    }
    float r = sm[0]; __syncthreads();
    return r;
}
__device__ inline float block_reduce_max_256(float v, float* sm) {
    int tid = threadIdx.x;
    sm[tid] = v; __syncthreads();
    for (int s = 128; s > 0; s >>= 1) {
        if (tid < s) sm[tid] = fmaxf(sm[tid], sm[tid + s]);
        __syncthreads();
    }
    float r = sm[0]; __syncthreads();
    return r;
}

// ---------------- fused weight prep: 7 weights in 3 launches ----------------
struct WPack {
    const float4* w[7];
    char4*        q[7];
    int           n4[7];
};

__global__ void wabs_partial_all(WPack p, float* __restrict__ part) {
    __shared__ float sm[256];
    const int wi = blockIdx.y;
    const float4* w = p.w[wi];
    const int n4 = p.n4[wi];
    float s = 0.f;
    for (int i = blockIdx.x * 256 + threadIdx.x; i < n4; i += 256 * 1024) {
        float4 v = w[i];
        s += fabsf(v.x) + fabsf(v.y) + fabsf(v.z) + fabsf(v.w);
    }
    float tot = block_reduce_sum_256(s, sm);
    if (threadIdx.x == 0) part[wi * 1024 + blockIdx.x] = tot;
}
__global__ void wabs_final_all(const float* __restrict__ part, WPack p,
                               float* __restrict__ wsc) {
    __shared__ float sm[256];
    const int wi = blockIdx.x;
    float s = 0.f;
    for (int i = threadIdx.x; i < 1024; i += 256) s += part[wi * 1024 + i];
    float tot = block_reduce_sum_256(s, sm);
    if (threadIdx.x == 0) wsc[wi] = tot / (float)(p.n4[wi] * 4) + 1e-8f;
}
__global__ void quant_w_all(WPack p, const float* __restrict__ wsc) {
    const int wi = blockIdx.y;
    const float ws = wsc[wi];
    const float4* w = p.w[wi];
    char4* q = p.q[wi];
    const int n4 = p.n4[wi];
    for (int i = blockIdx.x * 256 + threadIdx.x; i < n4; i += 256 * 2048) {
        float4 v = w[i];
        char4 c;
        c.x = (int8_t)fminf(1.f, fmaxf(-1.f, rintf(v.x / ws)));
        c.y = (int8_t)fminf(1.f, fmaxf(-1.f, rintf(v.y / ws)));
        c.z = (int8_t)fminf(1.f, fmaxf(-1.f, rintf(v.z / ws)));
        c.w = (int8_t)fminf(1.f, fmaxf(-1.f, rintf(v.w / ws)));
        q[i] = c;
    }
}

// ---------------- fused rmsnorm + activation quantization ----------------
__global__ void rmsnorm_quant(const float* __restrict__ x, const float* __restrict__ nw,
                              int8_t* __restrict__ q, float* __restrict__ ascale, int Kdim) {
    __shared__ float sm[256];
    int t = blockIdx.x;
    const float* row = x + (size_t)t * Kdim;
    float s = 0.f;
    for (int i = threadIdx.x; i < Kdim; i += 256) { float v = row[i]; s += v * v; }
    float tot = block_reduce_sum_256(s, sm);
    float rms = sqrtf(tot / (float)Kdim + 1e-6f);
    float m = 0.f;
    for (int i = threadIdx.x; i < Kdim; i += 256) {
        float h = row[i] / rms * nw[i];
        m = fmaxf(m, fabsf(h));
    }
    float amax = block_reduce_max_256(m, sm);
    float as = amax + 1e-8f;
    if (threadIdx.x == 0) ascale[t] = as;
    for (int i = threadIdx.x; i < Kdim; i += 256) {
        float h = row[i] / rms * nw[i];
        float v = rintf(fminf(127.f, fmaxf(-128.f, h / as * 127.f)));
        q[(size_t)t * Kdim + i] = (int8_t)v;
    }
}

__global__ void act_quant(const float* __restrict__ x, int8_t* __restrict__ q,
                          float* __restrict__ ascale, int Kdim) {
    __shared__ float sm[256];
    int t = blockIdx.x;
    const float* row = x + (size_t)t * Kdim;
    float m = 0.f;
    for (int i = threadIdx.x; i < Kdim; i += 256) m = fmaxf(m, fabsf(row[i]));
    float amax = block_reduce_max_256(m, sm);
    float as = amax + 1e-8f;
    if (threadIdx.x == 0) ascale[t] = as;
    for (int i = threadIdx.x; i < Kdim; i += 256) {
        float v = rintf(fminf(127.f, fmaxf(-128.f, row[i] / as * 127.f)));
        q[(size_t)t * Kdim + i] = (int8_t)v;
    }
}

// ---------------- int8 MFMA GEMM (verified; mode 3 added: fp16 store) ------
__global__ __launch_bounds__(256, 2) void gemm_mfma(
        const int8_t* __restrict__ Aq, const int8_t* __restrict__ Wq,
        float* __restrict__ out, const float* __restrict__ ascale,
        const float* __restrict__ wscale_p, const float* __restrict__ aux,
        int N, int K, int mode, int ws_shift) {
    __shared__ int8_t As[8192];   // 512 granules: [kc 0..3][row 0..127] * 16B
    __shared__ int8_t Bs[8192];
    const int tid = threadIdx.x;
    const int w = tid >> 6;
    const int l = tid & 63;
    const int wm = w & 1, wn = w >> 1;
    const int lk = l >> 5, lr = l & 31;
    const int m0blk = blockIdx.y * 128;
    const int n0blk = blockIdx.x * 128;

    const int8_t* ag0 = Aq + (size_t)(m0blk + l) * K + w * 16;
    const int8_t* ag1 = Aq + (size_t)(m0blk + 64 + l) * K + w * 16;
    const int8_t* bg0 = Wq + (size_t)(n0blk + l) * K + w * 16;
    const int8_t* bg1 = Wq + (size_t)(n0blk + 64 + l) * K + w * 16;
    int8_t* al = As + w * 2048;
    int8_t* bl = Bs + w * 2048;

    const int aoff = (lk * 128 + wm * 64 + lr) * 16;
    const int boff = (lk * 128 + wn * 64 + lr) * 16;

    v16i acc[2][2] = {};
    const int nkt = K >> 6;
    for (int kt = 0; kt < nkt; ++kt) {
        __syncthreads();
        const int kb = kt * 64;
        gll16(ag0 + kb, al);
        gll16(ag1 + kb, al + 1024);
        gll16(bg0 + kb, bl);
        gll16(bg1 + kb, bl + 1024);
        __syncthreads();
        #pragma unroll
        for (int ks = 0; ks < 2; ++ks) {
            v4i a0 = *(const v4i*)(As + aoff + ks * 4096);
            v4i a1 = *(const v4i*)(As + aoff + ks * 4096 + 512);
            v4i b0 = *(const v4i*)(Bs + boff + ks * 4096);
            v4i b1 = *(const v4i*)(Bs + boff + ks * 4096 + 512);
            acc[0][0] = __builtin_amdgcn_mfma_i32_32x32x32_i8(a0, b0, acc[0][0], 0, 0, 0);
            acc[0][1] = __builtin_amdgcn_mfma_i32_32x32x32_i8(a0, b1, acc[0][1], 0, 0, 0);
            acc[1][0] = __builtin_amdgcn_mfma_i32_32x32x32_i8(a1, b0, acc[1][0], 0, 0, 0);
            acc[1][1] = __builtin_amdgcn_mfma_i32_32x32x32_i8(a1, b1, acc[1][1], 0, 0, 0);
        }
    }

    #pragma unroll
    for (int mt = 0; mt < 2; ++mt) {
        const int mbase = m0blk + wm * 64 + mt * 32 + 4 * lk;
        #pragma unroll
        for (int nt = 0; nt < 2; ++nt) {
            const int n = n0blk + wn * 64 + nt * 32 + lr;
            const float ws = wscale_p[n >> ws_shift];
            v16i a = acc[mt][nt];
            #pragma unroll
            for (int r = 0; r < 16; ++r) {
                int m = mbase + (r & 3) + 8 * (r >> 2);
                float sc = ws * ascale[m] / 127.0f;
                float v = (float)a[r] * sc;
                size_t oi = (size_t)m * N + n;
                if (mode == 3) {
                    ((_Float16*)out)[oi] = (_Float16)v;   // fp16 QKV store
                } else {
                    if (mode == 1) v += aux[oi];
                    else if (mode == 2) v = v / (1.0f + expf(-v)) * aux[oi];
                    out[oi] = v;
                }
            }
        }
    }
}

// ---------------- fp16 MFMA flash attention (4-wave key-split) -------------
// Grid (S/32, B*H), 256 threads = 4 waves. All 4 waves own the SAME 32-query
// tile; wave wk handles key tiles kt = wk, wk+4, ... (<= qt) in a PRIVATE
// 18 KB LDS region -> no barriers in the main loop. Fixed m=0 online softmax
// (scores bounded, |s| ~<= 4) makes the accumulation linear, so per-wave
// partial (O, l) combine exactly by addition at the end (2 barriers total).
// QKV is fp16 (GEMM mode-3 store: identical rounding to the old in-kernel
// cvt). K staged via global_load_lds with source-side XOR pre-swizzle
// (linear LDS dest, rule 21); V reg-staged transposed (unchanged layout).
__global__ __launch_bounds__(256) void attn_mfma(const _Float16* __restrict__ QKV,
                                                 float* __restrict__ O) {
    __shared__ __align__(16) char LDS[73728];  // 4 waves * (8K K + 8K Vt + 2K P)
    const int tid  = threadIdx.x;
    const int wk   = tid >> 6;          // wave id = key phase 0..3
    const int l    = tid & 63;
    const int half = l >> 5;
    const int lr   = l & 31;
    const int qt   = (int)gridDim.x - 1 - (int)blockIdx.x;  // big tiles first
    const int bh   = blockIdx.y;
    const int b = bh >> 4, h = bh & 15;
    const int tok0 = b * S_DIM;
    const float scale = 0.08838834764831845f;  // 1/sqrt(128)

    char* myK = LDS + wk * 18432;
    char* myV = myK + 8192;
    char* myP = myK + 16384;

    // Q fragments (A-operand): lane holds Q[q=lr][d=16s+8*half+j], direct fp16
    v8h qa[8];
    {
        const _Float16* qrow = QKV + (size_t)(tok0 + qt * 32 + lr) * LDQ + h * HD_DIM;
        #pragma unroll
        for (int s = 0; s < 8; ++s)
            qa[s] = *(const v8h*)(qrow + s * 16 + half * 8);
    }
    v8h ones;
    #pragma unroll
    for (int j = 0; j < 8; ++j) ones[j] = (_Float16)1.0f;

    v16f oacc[4] = {zero16(), zero16(), zero16(), zero16()};
    v16f lacc = zero16();

    for (int kt = wk; kt <= qt; kt += 4) {
        const int kt0 = tok0 + kt * 32;

        // ---- V register loads first (overlap with K gll16 below) ----
        v8h va[4], vb[4];
        #pragma unroll
        for (int it = 0; it < 4; ++it) {
            int unit = it * 64 + l;
            int kp = unit & 15, g = unit >> 4;
            const _Float16* s0 = QKV + (size_t)(kt0 + 2 * kp) * LDQ + 2 * D_DIM
                                 + h * HD_DIM + g * 8;
            va[it] = *(const v8h*)s0;
            vb[it] = *(const v8h*)(s0 + LDQ);
        }
        // ---- K tile via global_load_lds: linear LDS dest, source pre-swizzle
        //      LDS slot (key, gs) receives logical granule gs ^ (key&15), so
        //      read side (gi ^ (lr&15)) stays byte-identical to verified code.
        #pragma unroll
        for (int it = 0; it < 8; ++it) {
            int unit = it * 64 + l;
            int key = unit >> 4, gs = unit & 15;
            int g = gs ^ (key & 15);
            gll16(QKV + (size_t)(kt0 + key) * LDQ + D_DIM + h * HD_DIM + g * 8,
                  myK + it * 1024);
        }
        // ---- V transpose pack into LDS: Vt[d][key], slot = keygranule^(d&3)
        #pragma unroll
        for (int it = 0; it < 4; ++it) {
            int unit = it * 64 + l;
            int kp = unit & 15, g = unit >> 4;
            int kg = kp >> 2, ko = (kp & 3) * 4;
            #pragma unroll
            for (int j = 0; j < 8; ++j) {
                int d = g * 8 + j;
                union { _Float16 hh[2]; unsigned u; } pk;
                pk.hh[0] = va[it][j];
                pk.hh[1] = vb[it][j];
                *(unsigned*)(myV + d * 64 + ((kg ^ (d & 3)) * 16) + ko) = pk.u;
            }
        }
        // wave-private wait: all gll16 K granules landed in myK
        asm volatile("s_waitcnt vmcnt(0)" ::: "memory");

        // ---- QK^T: S[q][key], contraction over d (8 MFMA steps) ----
        v16f sacc = zero16();
        #pragma unroll
        for (int s = 0; s < 8; ++s) {
            int gi = half + 2 * s;
            v8h kb = *(const v8h*)(myK + lr * 256 + ((gi ^ (lr & 15)) * 16));
            sacc = __builtin_amdgcn_mfma_f32_32x32x16_f16(qa[s], kb, sacc, 0, 0, 0);
        }

        // ---- P = exp(scale*s) (m=0), causal mask on diagonal tile; P -> LDS
        const bool diag = (kt == qt);
        #pragma unroll
        for (int r = 0; r < 16; ++r) {
            int row = (r & 3) + 8 * (r >> 2) + 4 * half;   // q offset
            float p = (!diag || lr <= row) ? __expf(sacc[r] * scale) : 0.0f;
            int kg2 = lr >> 3;
            *(_Float16*)(myP + row * 64 + ((kg2 ^ (row & 3)) * 16) + (lr & 7) * 2) = (_Float16)p;
        }

        // ---- PV + denominator: O[q][d] += P.V, l[q] += P.1 ----
        #pragma unroll
        for (int s2 = 0; s2 < 2; ++s2) {
            int pg = half + 2 * s2;
            v8h pa = *(const v8h*)(myP + lr * 64 + ((pg ^ (lr & 3)) * 16));
            lacc = __builtin_amdgcn_mfma_f32_32x32x16_f16(pa, ones, lacc, 0, 0, 0);
            #pragma unroll
            for (int nt = 0; nt < 4; ++nt) {
                int d = nt * 32 + lr;
                int kgv = half + 2 * s2;
                v8h vbf = *(const v8h*)(myV + d * 64 + ((kgv ^ (d & 3)) * 16));
                oacc[nt] = __builtin_amdgcn_mfma_f32_32x32x16_f16(pa, vbf, oacc[nt], 0, 0, 0);
            }
        }
    }

    // ---- combine partials across the 4 key-phase waves (linear softmax) ----
    __syncthreads();
    float* red = (float*)LDS;
    if (wk > 0) {
        float* reg = red + (size_t)(wk - 1) * 5120;   // 20 KB per region
        #pragma unroll
        for (int r = 0; r < 16; ++r) {
            int slot = half * 16 + r;
            #pragma unroll
            for (int nt = 0; nt < 4; ++nt)
                reg[(slot * 5 + nt) * 32 + lr] = oacc[nt][r];
            reg[(slot * 5 + 4) * 32 + lr] = lacc[r];
        }
    }
    __syncthreads();
    if (wk == 0) {
        #pragma unroll
        for (int w = 0; w < 3; ++w) {
            float* reg = red + (size_t)w * 5120;
            #pragma unroll
            for (int r = 0; r < 16; ++r) {
                int slot = half * 16 + r;
                #pragma unroll
                for (int nt = 0; nt < 4; ++nt)
                    oacc[nt][r] += reg[(slot * 5 + nt) * 32 + lr];
                lacc[r] += reg[(slot * 5 + 4) * 32 + lr];
            }
        }
        #pragma unroll
        for (int nt = 0; nt < 4; ++nt) {
            #pragma unroll
            for (int r = 0; r < 16; ++r) {
                int row = (r & 3) + 8 * (r >> 2) + 4 * half;
                O[(size_t)(tok0 + qt * 32 + row) * D_DIM + h * HD_DIM + nt * 32 + lr] =
                    oacc[nt][r] / lacc[r];
            }
        }
    }
}

extern "C" void kernel_launch(void* const* d_in, const int* in_sizes, int n_in,
                              void* d_out, int out_size, void* d_ws, size_t ws_size,
                              hipStream_t stream) {
    const float* x  = (const float*)d_in[0];
    const float* n1 = (const float*)d_in[8];
    const float* n2 = (const float*)d_in[9];
    float* out = (float*)d_out;

    // ---- workspace arena ----
    uint8_t* base = (uint8_t*)d_ws;
    size_t o = 0;
    auto alloc = [&](size_t bytes) -> uint8_t* {
        o = (o + 255) & ~(size_t)255;
        uint8_t* p = base + o;
        o += bytes;
        return p;
    };
    const size_t DD = (size_t)D_DIM * D_DIM;
    const size_t MD = (size_t)MLP_DIM * D_DIM;
    const size_t TD = (size_t)T_DIM * D_DIM;
    const size_t TM = (size_t)T_DIM * MLP_DIM;

    int8_t* wqkvQ = (int8_t*)alloc(3 * DD);   // q,k,v contiguous for fused GEMM
    int8_t* woQ   = (int8_t*)alloc(DD);
    int8_t* wgQ   = (int8_t*)alloc(MD);
    int8_t* wuQ   = (int8_t*)alloc(MD);
    int8_t* wdQ   = (int8_t*)alloc(MD);
    float*  wsc   = (float*)alloc(8 * sizeof(float));
    float*  part  = (float*)alloc(7 * 1024 * sizeof(float));
    float*  asc   = (float*)alloc(T_DIM * sizeof(float));
    int8_t* actQ  = (int8_t*)alloc(TM);
    float*  F     = (float*)alloc(5 * TD * sizeof(float));
    float* QKVf = F;            // [T, 6144] as fp16 now (uses half the region)
    float* AOf  = F + 3 * TD;
    float* x2f  = F + 4 * TD;
    float* yuf  = F;            // aliases QKV+AOf (4*TD = T*MLP floats); dead by then

    // ---- fused weight quantization: 3 launches for all 7 weights ----
    WPack p;
    p.w[0] = (const float4*)d_in[1];  p.q[0] = (char4*)wqkvQ;            p.n4[0] = (int)(DD >> 2);
    p.w[1] = (const float4*)d_in[2];  p.q[1] = (char4*)(wqkvQ + DD);     p.n4[1] = (int)(DD >> 2);
    p.w[2] = (const float4*)d_in[3];  p.q[2] = (char4*)(wqkvQ + 2 * DD); p.n4[2] = (int)(DD >> 2);
    p.w[3] = (const float4*)d_in[4];  p.q[3] = (char4*)woQ;              p.n4[3] = (int)(DD >> 2);
    p.w[4] = (const float4*)d_in[5];  p.q[4] = (char4*)wgQ;              p.n4[4] = (int)(MD >> 2);
    p.w[5] = (const float4*)d_in[6];  p.q[5] = (char4*)wuQ;              p.n4[5] = (int)(MD >> 2);
    p.w[6] = (const float4*)d_in[7];  p.q[6] = (char4*)wdQ;              p.n4[6] = (int)(MD >> 2);
    wabs_partial_all<<<dim3(1024, 7), 256, 0, stream>>>(p, part);
    wabs_final_all<<<7, 256, 0, stream>>>(part, p, wsc);
    quant_w_all<<<dim3(2048, 7), 256, 0, stream>>>(p, wsc);

    // ---- attention half ----
    rmsnorm_quant<<<T_DIM, 256, 0, stream>>>(x, n1, actQ, asc, D_DIM);
    dim3 gqkv(3 * D_DIM / 128, T_DIM / 128);
    gemm_mfma<<<gqkv, 256, 0, stream>>>(actQ, wqkvQ, QKVf, asc, wsc + 0, nullptr,
                                        3 * D_DIM, D_DIM, 3, 11);   // mode 3: fp16 out
    dim3 ga(S_DIM / 32, B_DIM * H_DIM);
    attn_mfma<<<ga, 256, 0, stream>>>((const _Float16*)QKVf, AOf);
    act_quant<<<T_DIM, 256, 0, stream>>>(AOf, actQ, asc, D_DIM);
    dim3 g1(D_DIM / 128, T_DIM / 128);
    gemm_mfma<<<g1, 256, 0, stream>>>(actQ, woQ, x2f, asc, wsc + 3, x,
                                      D_DIM, D_DIM, 1, 30);

    // ---- MLP half ----
    rmsnorm_quant<<<T_DIM, 256, 0, stream>>>(x2f, n2, actQ, asc, D_DIM);
    dim3 g2(MLP_DIM / 128, T_DIM / 128);
    gemm_mfma<<<g2, 256, 0, stream>>>(actQ, wuQ, yuf, asc, wsc + 5, nullptr,
                                      MLP_DIM, D_DIM, 0, 30);
    gemm_mfma<<<g2, 256, 0, stream>>>(actQ, wgQ, yuf, asc, wsc + 4, yuf,
                                      MLP_DIM, D_DIM, 2, 30);
    act_quant<<<T_DIM, 256, 0, stream>>>(yuf, actQ, asc, MLP_DIM);
    dim3 g3(D_DIM / 128, T_DIM / 128);
    gemm_mfma<<<g3, 256, 0, stream>>>(actQ, wdQ, out, asc, wsc + 6, x2f,
                                      D_DIM, MLP_DIM, 1, 30);
}

// Round 2
// 843.195 us; speedup vs baseline: 1.2286x; 1.0656x over previous
//
#include <hip/hip_runtime.h>
#include <cstdint>
#include <cmath>

#define D_DIM   2048
#define S_DIM   1024
#define B_DIM   2
#define H_DIM   16
#define HD_DIM  128
#define MLP_DIM 8192
#define T_DIM   (B_DIM * S_DIM)   // 2048 tokens
#define LDQ     (3 * D_DIM)       // fused QKV row stride (elements)

typedef int      v4i  __attribute__((ext_vector_type(4)));
typedef int      v16i __attribute__((ext_vector_type(16)));
typedef _Float16 v8h  __attribute__((ext_vector_type(8)));
typedef float    v16f __attribute__((ext_vector_type(16)));

__device__ inline void gll16(const void* g, void* l) {
    __builtin_amdgcn_global_load_lds(
        (__attribute__((address_space(1))) void*)g,
        (__attribute__((address_space(3))) void*)l, 16, 0, 0);
}

__device__ inline v16f zero16() {
    v16f z;
    #pragma unroll
    for (int i = 0; i < 16; ++i) z[i] = 0.f;
    return z;
}

// ---------------- block reductions (256 threads) ----------------
__device__ inline float block_reduce_sum_256(float v, float* sm) {
    int tid = threadIdx.x;
    sm[tid] = v; __syncthreads();
    for (int s = 128; s > 0; s >>= 1) {
        if (tid < s) sm[tid] += sm[tid + s];
        __syncthreads();
    }
    float r = sm[0]; __syncthreads();
    return r;
}
__device__ inline float block_reduce_max_256(float v, float* sm) {
    int tid = threadIdx.x;
    sm[tid] = v; __syncthreads();
    for (int s = 128; s > 0; s >>= 1) {
        if (tid < s) sm[tid] = fmaxf(sm[tid], sm[tid + s]);
        __syncthreads();
    }
    float r = sm[0]; __syncthreads();
    return r;
}

// ---------------- fused weight prep: 7 weights in 3 launches ----------------
struct WPack {
    const float4* w[7];
    char4*        q[7];
    int           n4[7];
};

__global__ void wabs_partial_all(WPack p, float* __restrict__ part) {
    __shared__ float sm[256];
    const int wi = blockIdx.y;
    const float4* w = p.w[wi];
    const int n4 = p.n4[wi];
    float s = 0.f;
    for (int i = blockIdx.x * 256 + threadIdx.x; i < n4; i += 256 * 1024) {
        float4 v = w[i];
        s += fabsf(v.x) + fabsf(v.y) + fabsf(v.z) + fabsf(v.w);
    }
    float tot = block_reduce_sum_256(s, sm);
    if (threadIdx.x == 0) part[wi * 1024 + blockIdx.x] = tot;
}
__global__ void wabs_final_all(const float* __restrict__ part, WPack p,
                               float* __restrict__ wsc) {
    __shared__ float sm[256];
    const int wi = blockIdx.x;
    float s = 0.f;
    for (int i = threadIdx.x; i < 1024; i += 256) s += part[wi * 1024 + i];
    float tot = block_reduce_sum_256(s, sm);
    if (threadIdx.x == 0) wsc[wi] = tot / (float)(p.n4[wi] * 4) + 1e-8f;
}
__global__ void quant_w_all(WPack p, const float* __restrict__ wsc) {
    const int wi = blockIdx.y;
    const float ws = wsc[wi];
    const float4* w = p.w[wi];
    char4* q = p.q[wi];
    const int n4 = p.n4[wi];
    for (int i = blockIdx.x * 256 + threadIdx.x; i < n4; i += 256 * 2048) {
        float4 v = w[i];
        char4 c;
        c.x = (int8_t)fminf(1.f, fmaxf(-1.f, rintf(v.x / ws)));
        c.y = (int8_t)fminf(1.f, fmaxf(-1.f, rintf(v.y / ws)));
        c.z = (int8_t)fminf(1.f, fmaxf(-1.f, rintf(v.z / ws)));
        c.w = (int8_t)fminf(1.f, fmaxf(-1.f, rintf(v.w / ws)));
        q[i] = c;
    }
}

// ---------------- fused rmsnorm + activation quantization ----------------
__global__ void rmsnorm_quant(const float* __restrict__ x, const float* __restrict__ nw,
                              int8_t* __restrict__ q, float* __restrict__ ascale, int Kdim) {
    __shared__ float sm[256];
    int t = blockIdx.x;
    const float* row = x + (size_t)t * Kdim;
    float s = 0.f;
    for (int i = threadIdx.x; i < Kdim; i += 256) { float v = row[i]; s += v * v; }
    float tot = block_reduce_sum_256(s, sm);
    float rms = sqrtf(tot / (float)Kdim + 1e-6f);
    float m = 0.f;
    for (int i = threadIdx.x; i < Kdim; i += 256) {
        float h = row[i] / rms * nw[i];
        m = fmaxf(m, fabsf(h));
    }
    float amax = block_reduce_max_256(m, sm);
    float as = amax + 1e-8f;
    if (threadIdx.x == 0) ascale[t] = as;
    for (int i = threadIdx.x; i < Kdim; i += 256) {
        float h = row[i] / rms * nw[i];
        float v = rintf(fminf(127.f, fmaxf(-128.f, h / as * 127.f)));
        q[(size_t)t * Kdim + i] = (int8_t)v;
    }
}

__global__ void act_quant(const float* __restrict__ x, int8_t* __restrict__ q,
                          float* __restrict__ ascale, int Kdim) {
    __shared__ float sm[256];
    int t = blockIdx.x;
    const float* row = x + (size_t)t * Kdim;
    float m = 0.f;
    for (int i = threadIdx.x; i < Kdim; i += 256) m = fmaxf(m, fabsf(row[i]));
    float amax = block_reduce_max_256(m, sm);
    float as = amax + 1e-8f;
    if (threadIdx.x == 0) ascale[t] = as;
    for (int i = threadIdx.x; i < Kdim; i += 256) {
        float v = rintf(fminf(127.f, fmaxf(-128.f, row[i] / as * 127.f)));
        q[(size_t)t * Kdim + i] = (int8_t)v;
    }
}

// ---------------- int8 MFMA GEMM, double-buffered prefetch pipeline --------
// 2-phase template: issue gll16 for next K-tile BEFORE ds_read+MFMA on the
// current one; single __syncthreads per K-step (its vmcnt(0)+lgkmcnt(0) drain
// IS the pipeline wait). Buffer written in iter t was last read in iter t-1
// before that barrier (barrier implies lgkmcnt(0)) -> race-free.
__global__ __launch_bounds__(256, 3) void gemm_mfma(
        const int8_t* __restrict__ Aq, const int8_t* __restrict__ Wq,
        float* __restrict__ out, const float* __restrict__ ascale,
        const float* __restrict__ wscale_p, const float* __restrict__ aux,
        int N, int K, int mode, int ws_shift) {
    __shared__ int8_t As[2][8192];   // 512 granules: [kc 0..3][row 0..127] * 16B
    __shared__ int8_t Bs[2][8192];
    const int tid = threadIdx.x;
    const int w = tid >> 6;
    const int l = tid & 63;
    const int wm = w & 1, wn = w >> 1;
    const int lk = l >> 5, lr = l & 31;
    const int m0blk = blockIdx.y * 128;
    const int n0blk = blockIdx.x * 128;

    const int8_t* ag0 = Aq + (size_t)(m0blk + l) * K + w * 16;
    const int8_t* ag1 = Aq + (size_t)(m0blk + 64 + l) * K + w * 16;
    const int8_t* bg0 = Wq + (size_t)(n0blk + l) * K + w * 16;
    const int8_t* bg1 = Wq + (size_t)(n0blk + 64 + l) * K + w * 16;

    const int aoff = (lk * 128 + wm * 64 + lr) * 16;
    const int boff = (lk * 128 + wn * 64 + lr) * 16;

    v16i acc[2][2] = {};
    const int nkt = K >> 6;

    {   // prologue: stage K-tile 0 into buf 0
        int8_t* al = As[0] + w * 2048;
        int8_t* bl = Bs[0] + w * 2048;
        gll16(ag0, al);
        gll16(ag1, al + 1024);
        gll16(bg0, bl);
        gll16(bg1, bl + 1024);
    }
    __syncthreads();

    int cur = 0;
    for (int kt = 0; kt < nkt; ++kt) {
        if (kt + 1 < nkt) {                    // prefetch next K-tile
            const int kb = (kt + 1) * 64;
            int8_t* al = As[cur ^ 1] + w * 2048;
            int8_t* bl = Bs[cur ^ 1] + w * 2048;
            gll16(ag0 + kb, al);
            gll16(ag1 + kb, al + 1024);
            gll16(bg0 + kb, bl);
            gll16(bg1 + kb, bl + 1024);
        }
        #pragma unroll
        for (int ks = 0; ks < 2; ++ks) {
            v4i a0 = *(const v4i*)(As[cur] + aoff + ks * 4096);
            v4i a1 = *(const v4i*)(As[cur] + aoff + ks * 4096 + 512);
            v4i b0 = *(const v4i*)(Bs[cur] + boff + ks * 4096);
            v4i b1 = *(const v4i*)(Bs[cur] + boff + ks * 4096 + 512);
            acc[0][0] = __builtin_amdgcn_mfma_i32_32x32x32_i8(a0, b0, acc[0][0], 0, 0, 0);
            acc[0][1] = __builtin_amdgcn_mfma_i32_32x32x32_i8(a0, b1, acc[0][1], 0, 0, 0);
            acc[1][0] = __builtin_amdgcn_mfma_i32_32x32x32_i8(a1, b0, acc[1][0], 0, 0, 0);
            acc[1][1] = __builtin_amdgcn_mfma_i32_32x32x32_i8(a1, b1, acc[1][1], 0, 0, 0);
        }
        __syncthreads();                       // drains vmcnt -> next buf ready
        cur ^= 1;
    }

    #pragma unroll
    for (int mt = 0; mt < 2; ++mt) {
        const int mbase = m0blk + wm * 64 + mt * 32 + 4 * lk;
        #pragma unroll
        for (int nt = 0; nt < 2; ++nt) {
            const int n = n0blk + wn * 64 + nt * 32 + lr;
            const float ws = wscale_p[n >> ws_shift];
            v16i a = acc[mt][nt];
            #pragma unroll
            for (int r = 0; r < 16; ++r) {
                int m = mbase + (r & 3) + 8 * (r >> 2);
                float sc = ws * ascale[m] / 127.0f;
                float v = (float)a[r] * sc;
                size_t oi = (size_t)m * N + n;
                if (mode == 3) {
                    ((_Float16*)out)[oi] = (_Float16)v;   // fp16 QKV store
                } else {
                    if (mode == 1) v += aux[oi];
                    else if (mode == 2) v = v / (1.0f + expf(-v)) * aux[oi];
                    out[oi] = v;
                }
            }
        }
    }
}

// ---------------- fused MLP up+gate GEMM (silu(x@wg^T)*(x@wu^T)) -----------
// Same tiling/layout as gemm_mfma, but two B-panels (wg, wu) share one
// A-panel and the silu*mul is applied in-register -> eliminates the 64 MB
// yuf intermediate write + re-read and one full A staging pass.
__global__ __launch_bounds__(256, 2) void gemm_mlp_fused(
        const int8_t* __restrict__ Aq, const int8_t* __restrict__ Wg,
        const int8_t* __restrict__ Wu, float* __restrict__ out,
        const float* __restrict__ ascale, const float* __restrict__ wsc_g,
        const float* __restrict__ wsc_u) {
    __shared__ int8_t As[2][8192];
    __shared__ int8_t Gs[2][8192];
    __shared__ int8_t Us[2][8192];
    const int tid = threadIdx.x;
    const int w = tid >> 6;
    const int l = tid & 63;
    const int wm = w & 1, wn = w >> 1;
    const int lk = l >> 5, lr = l & 31;
    const int m0blk = blockIdx.y * 128;
    const int n0blk = blockIdx.x * 128;
    const int K = D_DIM;

    const int8_t* ag0 = Aq + (size_t)(m0blk + l) * K + w * 16;
    const int8_t* ag1 = Aq + (size_t)(m0blk + 64 + l) * K + w * 16;
    const int8_t* gg0 = Wg + (size_t)(n0blk + l) * K + w * 16;
    const int8_t* gg1 = Wg + (size_t)(n0blk + 64 + l) * K + w * 16;
    const int8_t* ug0 = Wu + (size_t)(n0blk + l) * K + w * 16;
    const int8_t* ug1 = Wu + (size_t)(n0blk + 64 + l) * K + w * 16;

    const int aoff = (lk * 128 + wm * 64 + lr) * 16;
    const int boff = (lk * 128 + wn * 64 + lr) * 16;

    v16i accg[2][2] = {};
    v16i accu[2][2] = {};
    const int nkt = K >> 6;   // 32

    {   // prologue
        gll16(ag0, As[0] + w * 2048);
        gll16(ag1, As[0] + w * 2048 + 1024);
        gll16(gg0, Gs[0] + w * 2048);
        gll16(gg1, Gs[0] + w * 2048 + 1024);
        gll16(ug0, Us[0] + w * 2048);
        gll16(ug1, Us[0] + w * 2048 + 1024);
    }
    __syncthreads();

    int cur = 0;
    for (int kt = 0; kt < nkt; ++kt) {
        if (kt + 1 < nkt) {
            const int kb = (kt + 1) * 64;
            gll16(ag0 + kb, As[cur ^ 1] + w * 2048);
            gll16(ag1 + kb, As[cur ^ 1] + w * 2048 + 1024);
            gll16(gg0 + kb, Gs[cur ^ 1] + w * 2048);
            gll16(gg1 + kb, Gs[cur ^ 1] + w * 2048 + 1024);
            gll16(ug0 + kb, Us[cur ^ 1] + w * 2048);
            gll16(ug1 + kb, Us[cur ^ 1] + w * 2048 + 1024);
        }
        #pragma unroll
        for (int ks = 0; ks < 2; ++ks) {
            v4i a0 = *(const v4i*)(As[cur] + aoff + ks * 4096);
            v4i a1 = *(const v4i*)(As[cur] + aoff + ks * 4096 + 512);
            v4i g0 = *(const v4i*)(Gs[cur] + boff + ks * 4096);
            v4i g1 = *(const v4i*)(Gs[cur] + boff + ks * 4096 + 512);
            v4i u0 = *(const v4i*)(Us[cur] + boff + ks * 4096);
            v4i u1 = *(const v4i*)(Us[cur] + boff + ks * 4096 + 512);
            accg[0][0] = __builtin_amdgcn_mfma_i32_32x32x32_i8(a0, g0, accg[0][0], 0, 0, 0);
            accg[0][1] = __builtin_amdgcn_mfma_i32_32x32x32_i8(a0, g1, accg[0][1], 0, 0, 0);
            accg[1][0] = __builtin_amdgcn_mfma_i32_32x32x32_i8(a1, g0, accg[1][0], 0, 0, 0);
            accg[1][1] = __builtin_amdgcn_mfma_i32_32x32x32_i8(a1, g1, accg[1][1], 0, 0, 0);
            accu[0][0] = __builtin_amdgcn_mfma_i32_32x32x32_i8(a0, u0, accu[0][0], 0, 0, 0);
            accu[0][1] = __builtin_amdgcn_mfma_i32_32x32x32_i8(a0, u1, accu[0][1], 0, 0, 0);
            accu[1][0] = __builtin_amdgcn_mfma_i32_32x32x32_i8(a1, u0, accu[1][0], 0, 0, 0);
            accu[1][1] = __builtin_amdgcn_mfma_i32_32x32x32_i8(a1, u1, accu[1][1], 0, 0, 0);
        }
        __syncthreads();
        cur ^= 1;
    }

    const float wsg = *wsc_g;
    const float wsu = *wsc_u;
    #pragma unroll
    for (int mt = 0; mt < 2; ++mt) {
        const int mbase = m0blk + wm * 64 + mt * 32 + 4 * lk;
        #pragma unroll
        for (int nt = 0; nt < 2; ++nt) {
            const int n = n0blk + wn * 64 + nt * 32 + lr;
            v16i g = accg[mt][nt];
            v16i u = accu[mt][nt];
            #pragma unroll
            for (int r = 0; r < 16; ++r) {
                int m = mbase + (r & 3) + 8 * (r >> 2);
                float sc = ascale[m] / 127.0f;
                float gv = (float)g[r] * (wsg * sc);
                float uv = (float)u[r] * (wsu * sc);
                float v = gv / (1.0f + expf(-gv)) * uv;
                out[(size_t)m * MLP_DIM + n] = v;
            }
        }
    }
}

// ---------------- fp16 MFMA flash attention (4-wave key-split) -------------
// Grid (S/32, B*H), 256 threads = 4 waves. All 4 waves own the SAME 32-query
// tile; wave wk handles key tiles kt = wk, wk+4, ... (<= qt) in a PRIVATE
// 18 KB LDS region -> no barriers in the main loop. Fixed m=0 online softmax
// (scores bounded, |s| ~<= 4) makes the accumulation linear, so per-wave
// partial (O, l) combine exactly by addition at the end (2 barriers total).
__global__ __launch_bounds__(256) void attn_mfma(const _Float16* __restrict__ QKV,
                                                 float* __restrict__ O) {
    __shared__ __align__(16) char LDS[73728];  // 4 waves * (8K K + 8K Vt + 2K P)
    const int tid  = threadIdx.x;
    const int wk   = tid >> 6;          // wave id = key phase 0..3
    const int l    = tid & 63;
    const int half = l >> 5;
    const int lr   = l & 31;
    const int qt   = (int)gridDim.x - 1 - (int)blockIdx.x;  // big tiles first
    const int bh   = blockIdx.y;
    const int b = bh >> 4, h = bh & 15;
    const int tok0 = b * S_DIM;
    const float scale = 0.08838834764831845f;  // 1/sqrt(128)

    char* myK = LDS + wk * 18432;
    char* myV = myK + 8192;
    char* myP = myK + 16384;

    // Q fragments (A-operand): lane holds Q[q=lr][d=16s+8*half+j], direct fp16
    v8h qa[8];
    {
        const _Float16* qrow = QKV + (size_t)(tok0 + qt * 32 + lr) * LDQ + h * HD_DIM;
        #pragma unroll
        for (int s = 0; s < 8; ++s)
            qa[s] = *(const v8h*)(qrow + s * 16 + half * 8);
    }
    v8h ones;
    #pragma unroll
    for (int j = 0; j < 8; ++j) ones[j] = (_Float16)1.0f;

    v16f oacc[4] = {zero16(), zero16(), zero16(), zero16()};
    v16f lacc = zero16();

    for (int kt = wk; kt <= qt; kt += 4) {
        const int kt0 = tok0 + kt * 32;

        // ---- V register loads first (overlap with K gll16 below) ----
        v8h va[4], vb[4];
        #pragma unroll
        for (int it = 0; it < 4; ++it) {
            int unit = it * 64 + l;
            int kp = unit & 15, g = unit >> 4;
            const _Float16* s0 = QKV + (size_t)(kt0 + 2 * kp) * LDQ + 2 * D_DIM
                                 + h * HD_DIM + g * 8;
            va[it] = *(const v8h*)s0;
            vb[it] = *(const v8h*)(s0 + LDQ);
        }
        // ---- K tile via global_load_lds: linear LDS dest, source pre-swizzle
        #pragma unroll
        for (int it = 0; it < 8; ++it) {
            int unit = it * 64 + l;
            int key = unit >> 4, gs = unit & 15;
            int g = gs ^ (key & 15);
            gll16(QKV + (size_t)(kt0 + key) * LDQ + D_DIM + h * HD_DIM + g * 8,
                  myK + it * 1024);
        }
        // ---- V transpose pack into LDS: Vt[d][key], slot = keygranule^(d&3)
        #pragma unroll
        for (int it = 0; it < 4; ++it) {
            int unit = it * 64 + l;
            int kp = unit & 15, g = unit >> 4;
            int kg = kp >> 2, ko = (kp & 3) * 4;
            #pragma unroll
            for (int j = 0; j < 8; ++j) {
                int d = g * 8 + j;
                union { _Float16 hh[2]; unsigned u; } pk;
                pk.hh[0] = va[it][j];
                pk.hh[1] = vb[it][j];
                *(unsigned*)(myV + d * 64 + ((kg ^ (d & 3)) * 16) + ko) = pk.u;
            }
        }
        // wave-private wait: all gll16 K granules landed in myK
        asm volatile("s_waitcnt vmcnt(0)" ::: "memory");

        // ---- QK^T: S[q][key], contraction over d (8 MFMA steps) ----
        v16f sacc = zero16();
        #pragma unroll
        for (int s = 0; s < 8; ++s) {
            int gi = half + 2 * s;
            v8h kb = *(const v8h*)(myK + lr * 256 + ((gi ^ (lr & 15)) * 16));
            sacc = __builtin_amdgcn_mfma_f32_32x32x16_f16(qa[s], kb, sacc, 0, 0, 0);
        }

        // ---- P = exp(scale*s) (m=0), causal mask on diagonal tile; P -> LDS
        const bool diag = (kt == qt);
        #pragma unroll
        for (int r = 0; r < 16; ++r) {
            int row = (r & 3) + 8 * (r >> 2) + 4 * half;   // q offset
            float p = (!diag || lr <= row) ? __expf(sacc[r] * scale) : 0.0f;
            int kg2 = lr >> 3;
            *(_Float16*)(myP + row * 64 + ((kg2 ^ (row & 3)) * 16) + (lr & 7) * 2) = (_Float16)p;
        }

        // ---- PV + denominator: O[q][d] += P.V, l[q] += P.1 ----
        #pragma unroll
        for (int s2 = 0; s2 < 2; ++s2) {
            int pg = half + 2 * s2;
            v8h pa = *(const v8h*)(myP + lr * 64 + ((pg ^ (lr & 3)) * 16));
            lacc = __builtin_amdgcn_mfma_f32_32x32x16_f16(pa, ones, lacc, 0, 0, 0);
            #pragma unroll
            for (int nt = 0; nt < 4; ++nt) {
                int d = nt * 32 + lr;
                int kgv = half + 2 * s2;
                v8h vbf = *(const v8h*)(myV + d * 64 + ((kgv ^ (d & 3)) * 16));
                oacc[nt] = __builtin_amdgcn_mfma_f32_32x32x16_f16(pa, vbf, oacc[nt], 0, 0, 0);
            }
        }
    }

    // ---- combine partials across the 4 key-phase waves (linear softmax) ----
    __syncthreads();
    float* red = (float*)LDS;
    if (wk > 0) {
        float* reg = red + (size_t)(wk - 1) * 5120;   // 20 KB per region
        #pragma unroll
        for (int r = 0; r < 16; ++r) {
            int slot = half * 16 + r;
            #pragma unroll
            for (int nt = 0; nt < 4; ++nt)
                reg[(slot * 5 + nt) * 32 + lr] = oacc[nt][r];
            reg[(slot * 5 + 4) * 32 + lr] = lacc[r];
        }
    }
    __syncthreads();
    if (wk == 0) {
        #pragma unroll
        for (int w = 0; w < 3; ++w) {
            float* reg = red + (size_t)w * 5120;
            #pragma unroll
            for (int r = 0; r < 16; ++r) {
                int slot = half * 16 + r;
                #pragma unroll
                for (int nt = 0; nt < 4; ++nt)
                    oacc[nt][r] += reg[(slot * 5 + nt) * 32 + lr];
                lacc[r] += reg[(slot * 5 + 4) * 32 + lr];
            }
        }
        #pragma unroll
        for (int nt = 0; nt < 4; ++nt) {
            #pragma unroll
            for (int r = 0; r < 16; ++r) {
                int row = (r & 3) + 8 * (r >> 2) + 4 * half;
                O[(size_t)(tok0 + qt * 32 + row) * D_DIM + h * HD_DIM + nt * 32 + lr] =
                    oacc[nt][r] / lacc[r];
            }
        }
    }
}

extern "C" void kernel_launch(void* const* d_in, const int* in_sizes, int n_in,
                              void* d_out, int out_size, void* d_ws, size_t ws_size,
                              hipStream_t stream) {
    const float* x  = (const float*)d_in[0];
    const float* n1 = (const float*)d_in[8];
    const float* n2 = (const float*)d_in[9];
    float* out = (float*)d_out;

    // ---- workspace arena ----
    uint8_t* base = (uint8_t*)d_ws;
    size_t o = 0;
    auto alloc = [&](size_t bytes) -> uint8_t* {
        o = (o + 255) & ~(size_t)255;
        uint8_t* p = base + o;
        o += bytes;
        return p;
    };
    const size_t DD = (size_t)D_DIM * D_DIM;
    const size_t MD = (size_t)MLP_DIM * D_DIM;
    const size_t TD = (size_t)T_DIM * D_DIM;
    const size_t TM = (size_t)T_DIM * MLP_DIM;

    int8_t* wqkvQ = (int8_t*)alloc(3 * DD);   // q,k,v contiguous for fused GEMM
    int8_t* woQ   = (int8_t*)alloc(DD);
    int8_t* wgQ   = (int8_t*)alloc(MD);
    int8_t* wuQ   = (int8_t*)alloc(MD);
    int8_t* wdQ   = (int8_t*)alloc(MD);
    float*  wsc   = (float*)alloc(8 * sizeof(float));
    float*  part  = (float*)alloc(7 * 1024 * sizeof(float));
    float*  asc   = (float*)alloc(T_DIM * sizeof(float));
    int8_t* actQ  = (int8_t*)alloc(TM);
    float*  F     = (float*)alloc(5 * TD * sizeof(float));
    float* QKVf = F;            // [T, 6144] as fp16 (uses half the region)
    float* AOf  = F + 3 * TD;
    float* x2f  = F + 4 * TD;
    float* yuf  = F;            // aliases QKV+AOf (4*TD floats); dead by then

    // ---- fused weight quantization: 3 launches for all 7 weights ----
    WPack p;
    p.w[0] = (const float4*)d_in[1];  p.q[0] = (char4*)wqkvQ;            p.n4[0] = (int)(DD >> 2);
    p.w[1] = (const float4*)d_in[2];  p.q[1] = (char4*)(wqkvQ + DD);     p.n4[1] = (int)(DD >> 2);
    p.w[2] = (const float4*)d_in[3];  p.q[2] = (char4*)(wqkvQ + 2 * DD); p.n4[2] = (int)(DD >> 2);
    p.w[3] = (const float4*)d_in[4];  p.q[3] = (char4*)woQ;              p.n4[3] = (int)(DD >> 2);
    p.w[4] = (const float4*)d_in[5];  p.q[4] = (char4*)wgQ;              p.n4[4] = (int)(MD >> 2);
    p.w[5] = (const float4*)d_in[6];  p.q[5] = (char4*)wuQ;              p.n4[5] = (int)(MD >> 2);
    p.w[6] = (const float4*)d_in[7];  p.q[6] = (char4*)wdQ;              p.n4[6] = (int)(MD >> 2);
    wabs_partial_all<<<dim3(1024, 7), 256, 0, stream>>>(p, part);
    wabs_final_all<<<7, 256, 0, stream>>>(part, p, wsc);
    quant_w_all<<<dim3(2048, 7), 256, 0, stream>>>(p, wsc);

    // ---- attention half ----
    rmsnorm_quant<<<T_DIM, 256, 0, stream>>>(x, n1, actQ, asc, D_DIM);
    dim3 gqkv(3 * D_DIM / 128, T_DIM / 128);
    gemm_mfma<<<gqkv, 256, 0, stream>>>(actQ, wqkvQ, QKVf, asc, wsc + 0, nullptr,
                                        3 * D_DIM, D_DIM, 3, 11);   // mode 3: fp16 out
    dim3 ga(S_DIM / 32, B_DIM * H_DIM);
    attn_mfma<<<ga, 256, 0, stream>>>((const _Float16*)QKVf, AOf);
    act_quant<<<T_DIM, 256, 0, stream>>>(AOf, actQ, asc, D_DIM);
    dim3 g1(D_DIM / 128, T_DIM / 128);
    gemm_mfma<<<g1, 256, 0, stream>>>(actQ, woQ, x2f, asc, wsc + 3, x,
                                      D_DIM, D_DIM, 1, 30);

    // ---- MLP half ----
    rmsnorm_quant<<<T_DIM, 256, 0, stream>>>(x2f, n2, actQ, asc, D_DIM);
    dim3 g2(MLP_DIM / 128, T_DIM / 128);
    gemm_mlp_fused<<<g2, 256, 0, stream>>>(actQ, wgQ, wuQ, yuf, asc,
                                           wsc + 4, wsc + 5);
    act_quant<<<T_DIM, 256, 0, stream>>>(yuf, actQ, asc, MLP_DIM);
    dim3 g3(D_DIM / 128, T_DIM / 128);
    gemm_mfma<<<g3, 256, 0, stream>>>(actQ, wdQ, out, asc, wsc + 6, x2f,
                                      D_DIM, MLP_DIM, 1, 30);
}

// Round 3
// 791.280 us; speedup vs baseline: 1.3092x; 1.0656x over previous
//
#include <hip/hip_runtime.h>
#include <cstdint>
#include <cmath>

#define D_DIM   2048
#define S_DIM   1024
#define B_DIM   2
#define H_DIM   16
#define HD_DIM  128
#define MLP_DIM 8192
#define T_DIM   (B_DIM * S_DIM)   // 2048 tokens
#define LDQ     (3 * D_DIM)       // fused QKV row stride (elements)

typedef int      v4i  __attribute__((ext_vector_type(4)));
typedef int      v16i __attribute__((ext_vector_type(16)));
typedef _Float16 v8h  __attribute__((ext_vector_type(8)));
typedef float    v16f __attribute__((ext_vector_type(16)));

__device__ inline void gll16(const void* g, void* l) {
    __builtin_amdgcn_global_load_lds(
        (__attribute__((address_space(1))) void*)g,
        (__attribute__((address_space(3))) void*)l, 16, 0, 0);
}

__device__ inline v16f zero16() {
    v16f z;
    #pragma unroll
    for (int i = 0; i < 16; ++i) z[i] = 0.f;
    return z;
}

// int8 operands live PRE-PACKED in the GEMM tile order:
// per (128-row tile tr, 64-byte K-step kt): 8192 B = [kc 0..3][row 0..127]*16B
// char4 index: ((tr*nkt + kt)<<11) + (kc<<9) + (r<<2) + off4
// -> every gll16 in the GEMM reads 1024 CONTIGUOUS bytes (16 full lines).

// ---------------- block reductions (256 threads) ----------------
__device__ inline float block_reduce_sum_256(float v, float* sm) {
    int tid = threadIdx.x;
    sm[tid] = v; __syncthreads();
    for (int s = 128; s > 0; s >>= 1) {
        if (tid < s) sm[tid] += sm[tid + s];
        __syncthreads();
    }
    float r = sm[0]; __syncthreads();
    return r;
}
__device__ inline float block_reduce_max_256(float v, float* sm) {
    int tid = threadIdx.x;
    sm[tid] = v; __syncthreads();
    for (int s = 128; s > 0; s >>= 1) {
        if (tid < s) sm[tid] = fmaxf(sm[tid], sm[tid + s]);
        __syncthreads();
    }
    float r = sm[0]; __syncthreads();
    return r;
}

// ---------------- fused weight prep: 7 weights in 3 launches ----------------
struct WPack {
    const float4* w[7];
    char4*        q[7];
    int           n4[7];
    int           ksh[7];   // log2(K/4)
};

__global__ void wabs_partial_all(WPack p, float* __restrict__ part) {
    __shared__ float sm[256];
    const int wi = blockIdx.y;
    const float4* w = p.w[wi];
    const int n4 = p.n4[wi];
    float s = 0.f;
    for (int i = blockIdx.x * 256 + threadIdx.x; i < n4; i += 256 * 1024) {
        float4 v = w[i];
        s += fabsf(v.x) + fabsf(v.y) + fabsf(v.z) + fabsf(v.w);
    }
    float tot = block_reduce_sum_256(s, sm);
    if (threadIdx.x == 0) part[wi * 1024 + blockIdx.x] = tot;
}
__global__ void wabs_final_all(const float* __restrict__ part, WPack p,
                               float* __restrict__ wsc) {
    __shared__ float sm[256];
    const int wi = blockIdx.x;
    float s = 0.f;
    for (int i = threadIdx.x; i < 1024; i += 256) s += part[wi * 1024 + i];
    float tot = block_reduce_sum_256(s, sm);
    if (threadIdx.x == 0) wsc[wi] = tot / (float)(p.n4[wi] * 4) + 1e-8f;
}
__global__ void quant_w_all(WPack p, const float* __restrict__ wsc) {
    const int wi = blockIdx.y;
    const float ws = wsc[wi];
    const float4* w = p.w[wi];
    char4* q = p.q[wi];
    const int n4 = p.n4[wi];
    const int ksh = p.ksh[wi];
    const int kmask = (1 << ksh) - 1;
    const int nkt = 1 << (ksh - 4);   // K/64
    for (int i = blockIdx.x * 256 + threadIdx.x; i < n4; i += 256 * 2048) {
        float4 v = w[i];
        char4 c;
        c.x = (int8_t)fminf(1.f, fmaxf(-1.f, rintf(v.x / ws)));
        c.y = (int8_t)fminf(1.f, fmaxf(-1.f, rintf(v.y / ws)));
        c.z = (int8_t)fminf(1.f, fmaxf(-1.f, rintf(v.z / ws)));
        c.w = (int8_t)fminf(1.f, fmaxf(-1.f, rintf(v.w / ws)));
        int row = i >> ksh;
        int i4r = i & kmask;
        int kt = i4r >> 4, kc = (i4r >> 2) & 3, off4 = i4r & 3;
        size_t dst = ((size_t)((row >> 7) * nkt + kt) << 11)
                   + (kc << 9) + ((row & 127) << 2) + off4;
        q[dst] = c;
    }
}

// ---------------- fused rmsnorm + activation quantization ----------------
// sum/max passes scalar (bit-identical to verified numerics); only the
// store loop is grouped by 4 to emit packed char4 (same per-element values).
__global__ void rmsnorm_quant(const float* __restrict__ x, const float* __restrict__ nw,
                              int8_t* __restrict__ q, float* __restrict__ ascale, int Kdim) {
    __shared__ float sm[256];
    int t = blockIdx.x;
    const float* row = x + (size_t)t * Kdim;
    float s = 0.f;
    for (int i = threadIdx.x; i < Kdim; i += 256) { float v = row[i]; s += v * v; }
    float tot = block_reduce_sum_256(s, sm);
    float rms = sqrtf(tot / (float)Kdim + 1e-6f);
    float m = 0.f;
    for (int i = threadIdx.x; i < Kdim; i += 256) {
        float h = row[i] / rms * nw[i];
        m = fmaxf(m, fabsf(h));
    }
    float amax = block_reduce_max_256(m, sm);
    float as = amax + 1e-8f;
    if (threadIdx.x == 0) ascale[t] = as;
    char4* qc = (char4*)q;
    const int nkt = Kdim >> 6;
    const size_t tbase = (size_t)((t >> 7) * nkt) << 11;
    const int rr = (t & 127) << 2;
    for (int i4 = threadIdx.x; i4 < (Kdim >> 2); i4 += 256) {
        char4 c;
        int i = i4 << 2;
        float h0 = row[i + 0] / rms * nw[i + 0];
        float h1 = row[i + 1] / rms * nw[i + 1];
        float h2 = row[i + 2] / rms * nw[i + 2];
        float h3 = row[i + 3] / rms * nw[i + 3];
        c.x = (int8_t)rintf(fminf(127.f, fmaxf(-128.f, h0 / as * 127.f)));
        c.y = (int8_t)rintf(fminf(127.f, fmaxf(-128.f, h1 / as * 127.f)));
        c.z = (int8_t)rintf(fminf(127.f, fmaxf(-128.f, h2 / as * 127.f)));
        c.w = (int8_t)rintf(fminf(127.f, fmaxf(-128.f, h3 / as * 127.f)));
        size_t dst = tbase + ((size_t)(i4 >> 4) << 11) + (((i4 >> 2) & 3) << 9)
                   + rr + (i4 & 3);
        qc[dst] = c;
    }
}

__global__ void act_quant(const float* __restrict__ x, int8_t* __restrict__ q,
                          float* __restrict__ ascale, int Kdim) {
    __shared__ float sm[256];
    int t = blockIdx.x;
    const float* row = x + (size_t)t * Kdim;
    float m = 0.f;
    for (int i = threadIdx.x; i < Kdim; i += 256) m = fmaxf(m, fabsf(row[i]));
    float amax = block_reduce_max_256(m, sm);
    float as = amax + 1e-8f;
    if (threadIdx.x == 0) ascale[t] = as;
    char4* qc = (char4*)q;
    const int nkt = Kdim >> 6;
    const size_t tbase = (size_t)((t >> 7) * nkt) << 11;
    const int rr = (t & 127) << 2;
    for (int i4 = threadIdx.x; i4 < (Kdim >> 2); i4 += 256) {
        char4 c;
        int i = i4 << 2;
        c.x = (int8_t)rintf(fminf(127.f, fmaxf(-128.f, row[i + 0] / as * 127.f)));
        c.y = (int8_t)rintf(fminf(127.f, fmaxf(-128.f, row[i + 1] / as * 127.f)));
        c.z = (int8_t)rintf(fminf(127.f, fmaxf(-128.f, row[i + 2] / as * 127.f)));
        c.w = (int8_t)rintf(fminf(127.f, fmaxf(-128.f, row[i + 3] / as * 127.f)));
        size_t dst = tbase + ((size_t)(i4 >> 4) << 11) + (((i4 >> 2) & 3) << 9)
                   + rr + (i4 & 3);
        qc[dst] = c;
    }
}

// ---------------- int8 MFMA GEMM: packed tiles + counted-vmcnt pipeline ----
// 3-deep prefetch, counted s_waitcnt vmcnt(8/4/0) + raw s_barrier pairs:
// loads for tiles t+1,t+2 stay in flight across barriers. Buffer (t+2)%3
// written in iter t was last read in iter t-1 before its trailing barrier
// (lgkmcnt(0) pins ds_read completion) -> race-free.
__global__ __launch_bounds__(256, 3) void gemm_mfma(
        const int8_t* __restrict__ Aq, const int8_t* __restrict__ Wq,
        float* __restrict__ out, const float* __restrict__ ascale,
        const float* __restrict__ wscale_p, const float* __restrict__ aux,
        int N, int K, int mode, int ws_shift) {
    __shared__ int8_t As[3][8192];   // [kc 0..3][row 0..127] * 16B
    __shared__ int8_t Bs[3][8192];
    const int tid = threadIdx.x;
    const int w = tid >> 6;
    const int l = tid & 63;
    const int wm = w & 1, wn = w >> 1;
    const int lk = l >> 5, lr = l & 31;
    const int m0blk = blockIdx.y * 128;
    const int n0blk = blockIdx.x * 128;
    const int nkt = K >> 6;

    // packed sources: fully contiguous 1 KiB per gll16
    const int8_t* ag = Aq + ((size_t)blockIdx.y * nkt) * 8192 + w * 2048 + l * 16;
    const int8_t* bg = Wq + ((size_t)blockIdx.x * nkt) * 8192 + w * 2048 + l * 16;
    const int lo = w * 2048;   // wave-uniform LDS base

    const int aoff = (lk * 128 + wm * 64 + lr) * 16;
    const int boff = (lk * 128 + wn * 64 + lr) * 16;

    v16i acc[2][2] = {};

    auto stage = [&](int kt, int b) {
        const int8_t* a = ag + (size_t)kt * 8192;
        const int8_t* bs = bg + (size_t)kt * 8192;
        gll16(a,         As[b] + lo);
        gll16(a + 1024,  As[b] + lo + 1024);
        gll16(bs,        Bs[b] + lo);
        gll16(bs + 1024, Bs[b] + lo + 1024);
    };

    stage(0, 0);
    stage(1, 1);
    int cur = 0, nxt = 2;
    for (int kt = 0; kt < nkt; ++kt) {
        if (kt + 2 < nkt) {
            stage(kt + 2, nxt);
            asm volatile("s_waitcnt vmcnt(8)" ::: "memory");
        } else if (kt + 1 < nkt) {
            asm volatile("s_waitcnt vmcnt(4)" ::: "memory");
        } else {
            asm volatile("s_waitcnt vmcnt(0)" ::: "memory");
        }
        __builtin_amdgcn_s_barrier();          // tile kt visible to all waves
        #pragma unroll
        for (int ks = 0; ks < 2; ++ks) {
            v4i a0 = *(const v4i*)(As[cur] + aoff + ks * 4096);
            v4i a1 = *(const v4i*)(As[cur] + aoff + ks * 4096 + 512);
            v4i b0 = *(const v4i*)(Bs[cur] + boff + ks * 4096);
            v4i b1 = *(const v4i*)(Bs[cur] + boff + ks * 4096 + 512);
            acc[0][0] = __builtin_amdgcn_mfma_i32_32x32x32_i8(a0, b0, acc[0][0], 0, 0, 0);
            acc[0][1] = __builtin_amdgcn_mfma_i32_32x32x32_i8(a0, b1, acc[0][1], 0, 0, 0);
            acc[1][0] = __builtin_amdgcn_mfma_i32_32x32x32_i8(a1, b0, acc[1][0], 0, 0, 0);
            acc[1][1] = __builtin_amdgcn_mfma_i32_32x32x32_i8(a1, b1, acc[1][1], 0, 0, 0);
        }
        asm volatile("s_waitcnt lgkmcnt(0)" ::: "memory");
        __builtin_amdgcn_s_barrier();          // reads done -> buffer reusable
        cur = (cur == 2) ? 0 : cur + 1;
        nxt = (nxt == 2) ? 0 : nxt + 1;
    }

    #pragma unroll
    for (int mt = 0; mt < 2; ++mt) {
        const int mbase = m0blk + wm * 64 + mt * 32 + 4 * lk;
        #pragma unroll
        for (int nt = 0; nt < 2; ++nt) {
            const int n = n0blk + wn * 64 + nt * 32 + lr;
            const float ws = wscale_p[n >> ws_shift];
            v16i a = acc[mt][nt];
            #pragma unroll
            for (int r = 0; r < 16; ++r) {
                int m = mbase + (r & 3) + 8 * (r >> 2);
                float sc = ws * ascale[m] / 127.0f;
                float v = (float)a[r] * sc;
                size_t oi = (size_t)m * N + n;
                if (mode == 3) {
                    ((_Float16*)out)[oi] = (_Float16)v;   // fp16 QKV store
                } else {
                    if (mode == 1) v += aux[oi];
                    else if (mode == 2) v = v / (1.0f + expf(-v)) * aux[oi];
                    out[oi] = v;
                }
            }
        }
    }
}

// ---------------- fused MLP up+gate GEMM (silu(x@wg^T)*(x@wu^T)) -----------
__global__ __launch_bounds__(256, 2) void gemm_mlp_fused(
        const int8_t* __restrict__ Aq, const int8_t* __restrict__ Wg,
        const int8_t* __restrict__ Wu, float* __restrict__ out,
        const float* __restrict__ ascale, const float* __restrict__ wsc_g,
        const float* __restrict__ wsc_u) {
    __shared__ int8_t As[3][8192];
    __shared__ int8_t Gs[3][8192];
    __shared__ int8_t Us[3][8192];
    const int tid = threadIdx.x;
    const int w = tid >> 6;
    const int l = tid & 63;
    const int wm = w & 1, wn = w >> 1;
    const int lk = l >> 5, lr = l & 31;
    const int m0blk = blockIdx.y * 128;
    const int n0blk = blockIdx.x * 128;
    const int K = D_DIM;
    const int nkt = K >> 6;   // 32

    const int8_t* ag = Aq + ((size_t)blockIdx.y * nkt) * 8192 + w * 2048 + l * 16;
    const int8_t* gg = Wg + ((size_t)blockIdx.x * nkt) * 8192 + w * 2048 + l * 16;
    const int8_t* ug = Wu + ((size_t)blockIdx.x * nkt) * 8192 + w * 2048 + l * 16;
    const int lo = w * 2048;

    const int aoff = (lk * 128 + wm * 64 + lr) * 16;
    const int boff = (lk * 128 + wn * 64 + lr) * 16;

    v16i accg[2][2] = {};
    v16i accu[2][2] = {};

    auto stage = [&](int kt, int b) {
        const int8_t* a = ag + (size_t)kt * 8192;
        const int8_t* g = gg + (size_t)kt * 8192;
        const int8_t* u = ug + (size_t)kt * 8192;
        gll16(a,        As[b] + lo);
        gll16(a + 1024, As[b] + lo + 1024);
        gll16(g,        Gs[b] + lo);
        gll16(g + 1024, Gs[b] + lo + 1024);
        gll16(u,        Us[b] + lo);
        gll16(u + 1024, Us[b] + lo + 1024);
    };

    stage(0, 0);
    stage(1, 1);
    int cur = 0, nxt = 2;
    for (int kt = 0; kt < nkt; ++kt) {
        if (kt + 2 < nkt) {
            stage(kt + 2, nxt);
            asm volatile("s_waitcnt vmcnt(12)" ::: "memory");
        } else if (kt + 1 < nkt) {
            asm volatile("s_waitcnt vmcnt(6)" ::: "memory");
        } else {
            asm volatile("s_waitcnt vmcnt(0)" ::: "memory");
        }
        __builtin_amdgcn_s_barrier();
        #pragma unroll
        for (int ks = 0; ks < 2; ++ks) {
            v4i a0 = *(const v4i*)(As[cur] + aoff + ks * 4096);
            v4i a1 = *(const v4i*)(As[cur] + aoff + ks * 4096 + 512);
            v4i g0 = *(const v4i*)(Gs[cur] + boff + ks * 4096);
            v4i g1 = *(const v4i*)(Gs[cur] + boff + ks * 4096 + 512);
            v4i u0 = *(const v4i*)(Us[cur] + boff + ks * 4096);
            v4i u1 = *(const v4i*)(Us[cur] + boff + ks * 4096 + 512);
            accg[0][0] = __builtin_amdgcn_mfma_i32_32x32x32_i8(a0, g0, accg[0][0], 0, 0, 0);
            accg[0][1] = __builtin_amdgcn_mfma_i32_32x32x32_i8(a0, g1, accg[0][1], 0, 0, 0);
            accg[1][0] = __builtin_amdgcn_mfma_i32_32x32x32_i8(a1, g0, accg[1][0], 0, 0, 0);
            accg[1][1] = __builtin_amdgcn_mfma_i32_32x32x32_i8(a1, g1, accg[1][1], 0, 0, 0);
            accu[0][0] = __builtin_amdgcn_mfma_i32_32x32x32_i8(a0, u0, accu[0][0], 0, 0, 0);
            accu[0][1] = __builtin_amdgcn_mfma_i32_32x32x32_i8(a0, u1, accu[0][1], 0, 0, 0);
            accu[1][0] = __builtin_amdgcn_mfma_i32_32x32x32_i8(a1, u0, accu[1][0], 0, 0, 0);
            accu[1][1] = __builtin_amdgcn_mfma_i32_32x32x32_i8(a1, u1, accu[1][1], 0, 0, 0);
        }
        asm volatile("s_waitcnt lgkmcnt(0)" ::: "memory");
        __builtin_amdgcn_s_barrier();
        cur = (cur == 2) ? 0 : cur + 1;
        nxt = (nxt == 2) ? 0 : nxt + 1;
    }

    const float wsg = *wsc_g;
    const float wsu = *wsc_u;
    #pragma unroll
    for (int mt = 0; mt < 2; ++mt) {
        const int mbase = m0blk + wm * 64 + mt * 32 + 4 * lk;
        #pragma unroll
        for (int nt = 0; nt < 2; ++nt) {
            const int n = n0blk + wn * 64 + nt * 32 + lr;
            v16i g = accg[mt][nt];
            v16i u = accu[mt][nt];
            #pragma unroll
            for (int r = 0; r < 16; ++r) {
                int m = mbase + (r & 3) + 8 * (r >> 2);
                float sc = ascale[m] / 127.0f;
                float gv = (float)g[r] * (wsg * sc);
                float uv = (float)u[r] * (wsu * sc);
                float v = gv / (1.0f + expf(-gv)) * uv;
                out[(size_t)m * MLP_DIM + n] = v;
            }
        }
    }
}

// ---------------- fp16 MFMA flash attention (4-wave key-split) -------------
__global__ __launch_bounds__(256) void attn_mfma(const _Float16* __restrict__ QKV,
                                                 float* __restrict__ O) {
    __shared__ __align__(16) char LDS[73728];  // 4 waves * (8K K + 8K Vt + 2K P)
    const int tid  = threadIdx.x;
    const int wk   = tid >> 6;          // wave id = key phase 0..3
    const int l    = tid & 63;
    const int half = l >> 5;
    const int lr   = l & 31;
    const int qt   = (int)gridDim.x - 1 - (int)blockIdx.x;  // big tiles first
    const int bh   = blockIdx.y;
    const int b = bh >> 4, h = bh & 15;
    const int tok0 = b * S_DIM;
    const float scale = 0.08838834764831845f;  // 1/sqrt(128)

    char* myK = LDS + wk * 18432;
    char* myV = myK + 8192;
    char* myP = myK + 16384;

    v8h qa[8];
    {
        const _Float16* qrow = QKV + (size_t)(tok0 + qt * 32 + lr) * LDQ + h * HD_DIM;
        #pragma unroll
        for (int s = 0; s < 8; ++s)
            qa[s] = *(const v8h*)(qrow + s * 16 + half * 8);
    }
    v8h ones;
    #pragma unroll
    for (int j = 0; j < 8; ++j) ones[j] = (_Float16)1.0f;

    v16f oacc[4] = {zero16(), zero16(), zero16(), zero16()};
    v16f lacc = zero16();

    for (int kt = wk; kt <= qt; kt += 4) {
        const int kt0 = tok0 + kt * 32;

        v8h va[4], vb[4];
        #pragma unroll
        for (int it = 0; it < 4; ++it) {
            int unit = it * 64 + l;
            int kp = unit & 15, g = unit >> 4;
            const _Float16* s0 = QKV + (size_t)(kt0 + 2 * kp) * LDQ + 2 * D_DIM
                                 + h * HD_DIM + g * 8;
            va[it] = *(const v8h*)s0;
            vb[it] = *(const v8h*)(s0 + LDQ);
        }
        #pragma unroll
        for (int it = 0; it < 8; ++it) {
            int unit = it * 64 + l;
            int key = unit >> 4, gs = unit & 15;
            int g = gs ^ (key & 15);
            gll16(QKV + (size_t)(kt0 + key) * LDQ + D_DIM + h * HD_DIM + g * 8,
                  myK + it * 1024);
        }
        #pragma unroll
        for (int it = 0; it < 4; ++it) {
            int unit = it * 64 + l;
            int kp = unit & 15, g = unit >> 4;
            int kg = kp >> 2, ko = (kp & 3) * 4;
            #pragma unroll
            for (int j = 0; j < 8; ++j) {
                int d = g * 8 + j;
                union { _Float16 hh[2]; unsigned u; } pk;
                pk.hh[0] = va[it][j];
                pk.hh[1] = vb[it][j];
                *(unsigned*)(myV + d * 64 + ((kg ^ (d & 3)) * 16) + ko) = pk.u;
            }
        }
        asm volatile("s_waitcnt vmcnt(0)" ::: "memory");

        v16f sacc = zero16();
        #pragma unroll
        for (int s = 0; s < 8; ++s) {
            int gi = half + 2 * s;
            v8h kb = *(const v8h*)(myK + lr * 256 + ((gi ^ (lr & 15)) * 16));
            sacc = __builtin_amdgcn_mfma_f32_32x32x16_f16(qa[s], kb, sacc, 0, 0, 0);
        }

        const bool diag = (kt == qt);
        #pragma unroll
        for (int r = 0; r < 16; ++r) {
            int row = (r & 3) + 8 * (r >> 2) + 4 * half;   // q offset
            float p = (!diag || lr <= row) ? __expf(sacc[r] * scale) : 0.0f;
            int kg2 = lr >> 3;
            *(_Float16*)(myP + row * 64 + ((kg2 ^ (row & 3)) * 16) + (lr & 7) * 2) = (_Float16)p;
        }

        #pragma unroll
        for (int s2 = 0; s2 < 2; ++s2) {
            int pg = half + 2 * s2;
            v8h pa = *(const v8h*)(myP + lr * 64 + ((pg ^ (lr & 3)) * 16));
            lacc = __builtin_amdgcn_mfma_f32_32x32x16_f16(pa, ones, lacc, 0, 0, 0);
            #pragma unroll
            for (int nt = 0; nt < 4; ++nt) {
                int d = nt * 32 + lr;
                int kgv = half + 2 * s2;
                v8h vbf = *(const v8h*)(myV + d * 64 + ((kgv ^ (d & 3)) * 16));
                oacc[nt] = __builtin_amdgcn_mfma_f32_32x32x16_f16(pa, vbf, oacc[nt], 0, 0, 0);
            }
        }
    }

    __syncthreads();
    float* red = (float*)LDS;
    if (wk > 0) {
        float* reg = red + (size_t)(wk - 1) * 5120;   // 20 KB per region
        #pragma unroll
        for (int r = 0; r < 16; ++r) {
            int slot = half * 16 + r;
            #pragma unroll
            for (int nt = 0; nt < 4; ++nt)
                reg[(slot * 5 + nt) * 32 + lr] = oacc[nt][r];
            reg[(slot * 5 + 4) * 32 + lr] = lacc[r];
        }
    }
    __syncthreads();
    if (wk == 0) {
        #pragma unroll
        for (int w = 0; w < 3; ++w) {
            float* reg = red + (size_t)w * 5120;
            #pragma unroll
            for (int r = 0; r < 16; ++r) {
                int slot = half * 16 + r;
                #pragma unroll
                for (int nt = 0; nt < 4; ++nt)
                    oacc[nt][r] += reg[(slot * 5 + nt) * 32 + lr];
                lacc[r] += reg[(slot * 5 + 4) * 32 + lr];
            }
        }
        #pragma unroll
        for (int nt = 0; nt < 4; ++nt) {
            #pragma unroll
            for (int r = 0; r < 16; ++r) {
                int row = (r & 3) + 8 * (r >> 2) + 4 * half;
                O[(size_t)(tok0 + qt * 32 + row) * D_DIM + h * HD_DIM + nt * 32 + lr] =
                    oacc[nt][r] / lacc[r];
            }
        }
    }
}

extern "C" void kernel_launch(void* const* d_in, const int* in_sizes, int n_in,
                              void* d_out, int out_size, void* d_ws, size_t ws_size,
                              hipStream_t stream) {
    const float* x  = (const float*)d_in[0];
    const float* n1 = (const float*)d_in[8];
    const float* n2 = (const float*)d_in[9];
    float* out = (float*)d_out;

    // ---- workspace arena ----
    uint8_t* base = (uint8_t*)d_ws;
    size_t o = 0;
    auto alloc = [&](size_t bytes) -> uint8_t* {
        o = (o + 255) & ~(size_t)255;
        uint8_t* p = base + o;
        o += bytes;
        return p;
    };
    const size_t DD = (size_t)D_DIM * D_DIM;
    const size_t MD = (size_t)MLP_DIM * D_DIM;
    const size_t TD = (size_t)T_DIM * D_DIM;
    const size_t TM = (size_t)T_DIM * MLP_DIM;

    int8_t* wqkvQ = (int8_t*)alloc(3 * DD);   // q,k,v contiguous for fused GEMM
    int8_t* woQ   = (int8_t*)alloc(DD);
    int8_t* wgQ   = (int8_t*)alloc(MD);
    int8_t* wuQ   = (int8_t*)alloc(MD);
    int8_t* wdQ   = (int8_t*)alloc(MD);
    float*  wsc   = (float*)alloc(8 * sizeof(float));
    float*  part  = (float*)alloc(7 * 1024 * sizeof(float));
    float*  asc   = (float*)alloc(T_DIM * sizeof(float));
    int8_t* actQ  = (int8_t*)alloc(TM);
    float*  F     = (float*)alloc(5 * TD * sizeof(float));
    float* QKVf = F;            // [T, 6144] as fp16 (uses half the region)
    float* AOf  = F + 3 * TD;
    float* x2f  = F + 4 * TD;
    float* yuf  = F;            // aliases QKV+AOf (4*TD floats); dead by then

    // ---- fused weight quantization: 3 launches for all 7 weights ----
    WPack p;
    p.w[0] = (const float4*)d_in[1];  p.q[0] = (char4*)wqkvQ;            p.n4[0] = (int)(DD >> 2);
    p.w[1] = (const float4*)d_in[2];  p.q[1] = (char4*)(wqkvQ + DD);     p.n4[1] = (int)(DD >> 2);
    p.w[2] = (const float4*)d_in[3];  p.q[2] = (char4*)(wqkvQ + 2 * DD); p.n4[2] = (int)(DD >> 2);
    p.w[3] = (const float4*)d_in[4];  p.q[3] = (char4*)woQ;              p.n4[3] = (int)(DD >> 2);
    p.w[4] = (const float4*)d_in[5];  p.q[4] = (char4*)wgQ;              p.n4[4] = (int)(MD >> 2);
    p.w[5] = (const float4*)d_in[6];  p.q[5] = (char4*)wuQ;              p.n4[5] = (int)(MD >> 2);
    p.w[6] = (const float4*)d_in[7];  p.q[6] = (char4*)wdQ;              p.n4[6] = (int)(MD >> 2);
    // K per weight: wq/wk/wv/wo/wg/wu = 2048 (K/4 = 512, shift 9); wd = 8192 (shift 11)
    p.ksh[0] = p.ksh[1] = p.ksh[2] = p.ksh[3] = p.ksh[4] = p.ksh[5] = 9;
    p.ksh[6] = 11;
    wabs_partial_all<<<dim3(1024, 7), 256, 0, stream>>>(p, part);
    wabs_final_all<<<7, 256, 0, stream>>>(part, p, wsc);
    quant_w_all<<<dim3(2048, 7), 256, 0, stream>>>(p, wsc);

    // ---- attention half ----
    rmsnorm_quant<<<T_DIM, 256, 0, stream>>>(x, n1, actQ, asc, D_DIM);
    dim3 gqkv(3 * D_DIM / 128, T_DIM / 128);
    gemm_mfma<<<gqkv, 256, 0, stream>>>(actQ, wqkvQ, QKVf, asc, wsc + 0, nullptr,
                                        3 * D_DIM, D_DIM, 3, 11);   // mode 3: fp16 out
    dim3 ga(S_DIM / 32, B_DIM * H_DIM);
    attn_mfma<<<ga, 256, 0, stream>>>((const _Float16*)QKVf, AOf);
    act_quant<<<T_DIM, 256, 0, stream>>>(AOf, actQ, asc, D_DIM);
    dim3 g1(D_DIM / 128, T_DIM / 128);
    gemm_mfma<<<g1, 256, 0, stream>>>(actQ, woQ, x2f, asc, wsc + 3, x,
                                      D_DIM, D_DIM, 1, 30);

    // ---- MLP half ----
    rmsnorm_quant<<<T_DIM, 256, 0, stream>>>(x2f, n2, actQ, asc, D_DIM);
    dim3 g2(MLP_DIM / 128, T_DIM / 128);
    gemm_mlp_fused<<<g2, 256, 0, stream>>>(actQ, wgQ, wuQ, yuf, asc,
                                           wsc + 4, wsc + 5);
    act_quant<<<T_DIM, 256, 0, stream>>>(yuf, actQ, asc, MLP_DIM);
    dim3 g3(D_DIM / 128, T_DIM / 128);
    gemm_mfma<<<g3, 256, 0, stream>>>(actQ, wdQ, out, asc, wsc + 6, x2f,
                                      D_DIM, MLP_DIM, 1, 30);
}

// Round 4
// 745.125 us; speedup vs baseline: 1.3903x; 1.0619x over previous
//
#include <hip/hip_runtime.h>
#include <cstdint>
#include <cmath>

#define D_DIM   2048
#define S_DIM   1024
#define B_DIM   2
#define H_DIM   16
#define HD_DIM  128
#define MLP_DIM 8192
#define T_DIM   (B_DIM * S_DIM)   // 2048 tokens
#define LDQ     (3 * D_DIM)       // fused QKV row stride (elements)

typedef int      v4i  __attribute__((ext_vector_type(4)));
typedef int      v16i __attribute__((ext_vector_type(16)));
typedef _Float16 v8h  __attribute__((ext_vector_type(8)));
typedef float    v16f __attribute__((ext_vector_type(16)));

__device__ inline void gll16(const void* g, void* l) {
    __builtin_amdgcn_global_load_lds(
        (__attribute__((address_space(1))) void*)g,
        (__attribute__((address_space(3))) void*)l, 16, 0, 0);
}

__device__ inline v16f zero16() {
    v16f z;
    #pragma unroll
    for (int i = 0; i < 16; ++i) z[i] = 0.f;
    return z;
}

// int8 operands live PRE-PACKED in the GEMM tile order:
// per (128-row tile tr, 64-byte K-step kt): 8192 B = [kc 0..3][row 0..127]*16B
// char4 index: ((tr*nkt + kt)<<11) + (kc<<9) + (r<<2) + off4
// -> every gll16 in the GEMM reads 1024 CONTIGUOUS bytes (16 full lines).

// ---------------- block reductions (256 threads) ----------------
__device__ inline float block_reduce_sum_256(float v, float* sm) {
    int tid = threadIdx.x;
    sm[tid] = v; __syncthreads();
    for (int s = 128; s > 0; s >>= 1) {
        if (tid < s) sm[tid] += sm[tid + s];
        __syncthreads();
    }
    float r = sm[0]; __syncthreads();
    return r;
}
__device__ inline float block_reduce_max_256(float v, float* sm) {
    int tid = threadIdx.x;
    sm[tid] = v; __syncthreads();
    for (int s = 128; s > 0; s >>= 1) {
        if (tid < s) sm[tid] = fmaxf(sm[tid], sm[tid + s]);
        __syncthreads();
    }
    float r = sm[0]; __syncthreads();
    return r;
}

// ---------------- fused weight prep: 7 weights in 3 launches ----------------
struct WPack {
    const float4* w[7];
    char4*        q[7];
    int           n4[7];
    int           ksh[7];   // log2(K/4)
};

__global__ void wabs_partial_all(WPack p, float* __restrict__ part) {
    __shared__ float sm[256];
    const int wi = blockIdx.y;
    const float4* w = p.w[wi];
    const int n4 = p.n4[wi];
    float s = 0.f;
    for (int i = blockIdx.x * 256 + threadIdx.x; i < n4; i += 256 * 1024) {
        float4 v = w[i];
        s += fabsf(v.x) + fabsf(v.y) + fabsf(v.z) + fabsf(v.w);
    }
    float tot = block_reduce_sum_256(s, sm);
    if (threadIdx.x == 0) part[wi * 1024 + blockIdx.x] = tot;
}
__global__ void wabs_final_all(const float* __restrict__ part, WPack p,
                               float* __restrict__ wsc) {
    __shared__ float sm[256];
    const int wi = blockIdx.x;
    float s = 0.f;
    for (int i = threadIdx.x; i < 1024; i += 256) s += part[wi * 1024 + i];
    float tot = block_reduce_sum_256(s, sm);
    if (threadIdx.x == 0) wsc[wi] = tot / (float)(p.n4[wi] * 4) + 1e-8f;
}
__global__ void quant_w_all(WPack p, const float* __restrict__ wsc) {
    const int wi = blockIdx.y;
    const float ws = wsc[wi];
    const float4* w = p.w[wi];
    char4* q = p.q[wi];
    const int n4 = p.n4[wi];
    const int ksh = p.ksh[wi];
    const int kmask = (1 << ksh) - 1;
    const int nkt = 1 << (ksh - 4);   // K/64
    for (int i = blockIdx.x * 256 + threadIdx.x; i < n4; i += 256 * 2048) {
        float4 v = w[i];
        char4 c;
        c.x = (int8_t)fminf(1.f, fmaxf(-1.f, rintf(v.x / ws)));
        c.y = (int8_t)fminf(1.f, fmaxf(-1.f, rintf(v.y / ws)));
        c.z = (int8_t)fminf(1.f, fmaxf(-1.f, rintf(v.z / ws)));
        c.w = (int8_t)fminf(1.f, fmaxf(-1.f, rintf(v.w / ws)));
        int row = i >> ksh;
        int i4r = i & kmask;
        int kt = i4r >> 4, kc = (i4r >> 2) & 3, off4 = i4r & 3;
        size_t dst = ((size_t)((row >> 7) * nkt + kt) << 11)
                   + (kc << 9) + ((row & 127) << 2) + off4;
        q[dst] = c;
    }
}

// ---------------- fused rmsnorm + activation quantization ----------------
__global__ void rmsnorm_quant(const float* __restrict__ x, const float* __restrict__ nw,
                              int8_t* __restrict__ q, float* __restrict__ ascale, int Kdim) {
    __shared__ float sm[256];
    int t = blockIdx.x;
    const float* row = x + (size_t)t * Kdim;
    float s = 0.f;
    for (int i = threadIdx.x; i < Kdim; i += 256) { float v = row[i]; s += v * v; }
    float tot = block_reduce_sum_256(s, sm);
    float rms = sqrtf(tot / (float)Kdim + 1e-6f);
    float m = 0.f;
    for (int i = threadIdx.x; i < Kdim; i += 256) {
        float h = row[i] / rms * nw[i];
        m = fmaxf(m, fabsf(h));
    }
    float amax = block_reduce_max_256(m, sm);
    float as = amax + 1e-8f;
    if (threadIdx.x == 0) ascale[t] = as;
    char4* qc = (char4*)q;
    const int nkt = Kdim >> 6;
    const size_t tbase = (size_t)((t >> 7) * nkt) << 11;
    const int rr = (t & 127) << 2;
    for (int i4 = threadIdx.x; i4 < (Kdim >> 2); i4 += 256) {
        char4 c;
        int i = i4 << 2;
        float h0 = row[i + 0] / rms * nw[i + 0];
        float h1 = row[i + 1] / rms * nw[i + 1];
        float h2 = row[i + 2] / rms * nw[i + 2];
        float h3 = row[i + 3] / rms * nw[i + 3];
        c.x = (int8_t)rintf(fminf(127.f, fmaxf(-128.f, h0 / as * 127.f)));
        c.y = (int8_t)rintf(fminf(127.f, fmaxf(-128.f, h1 / as * 127.f)));
        c.z = (int8_t)rintf(fminf(127.f, fmaxf(-128.f, h2 / as * 127.f)));
        c.w = (int8_t)rintf(fminf(127.f, fmaxf(-128.f, h3 / as * 127.f)));
        size_t dst = tbase + ((size_t)(i4 >> 4) << 11) + (((i4 >> 2) & 3) << 9)
                   + rr + (i4 & 3);
        qc[dst] = c;
    }
}

__global__ void act_quant(const float* __restrict__ x, int8_t* __restrict__ q,
                          float* __restrict__ ascale, int Kdim) {
    __shared__ float sm[256];
    int t = blockIdx.x;
    const float* row = x + (size_t)t * Kdim;
    float m = 0.f;
    for (int i = threadIdx.x; i < Kdim; i += 256) m = fmaxf(m, fabsf(row[i]));
    float amax = block_reduce_max_256(m, sm);
    float as = amax + 1e-8f;
    if (threadIdx.x == 0) ascale[t] = as;
    char4* qc = (char4*)q;
    const int nkt = Kdim >> 6;
    const size_t tbase = (size_t)((t >> 7) * nkt) << 11;
    const int rr = (t & 127) << 2;
    for (int i4 = threadIdx.x; i4 < (Kdim >> 2); i4 += 256) {
        char4 c;
        int i = i4 << 2;
        c.x = (int8_t)rintf(fminf(127.f, fmaxf(-128.f, row[i + 0] / as * 127.f)));
        c.y = (int8_t)rintf(fminf(127.f, fmaxf(-128.f, row[i + 1] / as * 127.f)));
        c.z = (int8_t)rintf(fminf(127.f, fmaxf(-128.f, row[i + 2] / as * 127.f)));
        c.w = (int8_t)rintf(fminf(127.f, fmaxf(-128.f, row[i + 3] / as * 127.f)));
        size_t dst = tbase + ((size_t)(i4 >> 4) << 11) + (((i4 >> 2) & 3) << 9)
                   + rr + (i4 & 3);
        qc[dst] = c;
    }
}

// XCD-aware chunked swizzle (T1). Requirements per launch:
// cw | gridDim.x, ch | gridDim.y, (gx/cw)*(gy/ch)*gz == 8.
// Consecutive-dispatch blocks (round-robin XCDs) then give each XCD a compact
// cw x ch tile chunk -> per-XCD L2 panel footprint minimized. Bijective.

// ---------------- int8 MFMA GEMM: packed tiles + counted-vmcnt pipeline ----
__global__ __launch_bounds__(256, 3) void gemm_mfma(
        const int8_t* __restrict__ Aq, const int8_t* __restrict__ Wq,
        float* __restrict__ out, const float* __restrict__ ascale,
        const float* __restrict__ wscale_p, const float* __restrict__ aux,
        int N, int K, int mode, int ws_shift, int cw, int ch) {
    __shared__ int8_t As[3][8192];   // [kc 0..3][row 0..127] * 16B
    __shared__ int8_t Bs[3][8192];
    const int tid = threadIdx.x;
    const int w = tid >> 6;
    const int l = tid & 63;
    const int wm = w & 1, wn = w >> 1;
    const int lk = l >> 5, lr = l & 31;
    const int nkt = K >> 6;

    // swizzled block coords
    const int gx = gridDim.x;
    const int ncx = gx / cw;
    int id = (int)blockIdx.y * gx + (int)blockIdx.x;
    int c = id & 7, j = id >> 3;
    int by = (c / ncx) * ch + j / cw;
    int bx = (c % ncx) * cw + j % cw;
    const int m0blk = by * 128;
    const int n0blk = bx * 128;

    // packed sources: fully contiguous 1 KiB per gll16
    const int8_t* ag = Aq + ((size_t)by * nkt) * 8192 + w * 2048 + l * 16;
    const int8_t* bg = Wq + ((size_t)bx * nkt) * 8192 + w * 2048 + l * 16;
    const int lo = w * 2048;   // wave-uniform LDS base

    const int aoff = (lk * 128 + wm * 64 + lr) * 16;
    const int boff = (lk * 128 + wn * 64 + lr) * 16;

    v16i acc[2][2] = {};

    auto stage = [&](int kt, int b) {
        const int8_t* a = ag + (size_t)kt * 8192;
        const int8_t* bs = bg + (size_t)kt * 8192;
        gll16(a,         As[b] + lo);
        gll16(a + 1024,  As[b] + lo + 1024);
        gll16(bs,        Bs[b] + lo);
        gll16(bs + 1024, Bs[b] + lo + 1024);
    };

    stage(0, 0);
    stage(1, 1);
    int cur = 0, nxt = 2;
    for (int kt = 0; kt < nkt; ++kt) {
        if (kt + 2 < nkt) {
            stage(kt + 2, nxt);
            asm volatile("s_waitcnt vmcnt(8)" ::: "memory");
        } else if (kt + 1 < nkt) {
            asm volatile("s_waitcnt vmcnt(4)" ::: "memory");
        } else {
            asm volatile("s_waitcnt vmcnt(0)" ::: "memory");
        }
        __builtin_amdgcn_s_barrier();          // tile kt visible to all waves
        #pragma unroll
        for (int ks = 0; ks < 2; ++ks) {
            v4i a0 = *(const v4i*)(As[cur] + aoff + ks * 4096);
            v4i a1 = *(const v4i*)(As[cur] + aoff + ks * 4096 + 512);
            v4i b0 = *(const v4i*)(Bs[cur] + boff + ks * 4096);
            v4i b1 = *(const v4i*)(Bs[cur] + boff + ks * 4096 + 512);
            acc[0][0] = __builtin_amdgcn_mfma_i32_32x32x32_i8(a0, b0, acc[0][0], 0, 0, 0);
            acc[0][1] = __builtin_amdgcn_mfma_i32_32x32x32_i8(a0, b1, acc[0][1], 0, 0, 0);
            acc[1][0] = __builtin_amdgcn_mfma_i32_32x32x32_i8(a1, b0, acc[1][0], 0, 0, 0);
            acc[1][1] = __builtin_amdgcn_mfma_i32_32x32x32_i8(a1, b1, acc[1][1], 0, 0, 0);
        }
        asm volatile("s_waitcnt lgkmcnt(0)" ::: "memory");
        __builtin_amdgcn_s_barrier();          // reads done -> buffer reusable
        cur = (cur == 2) ? 0 : cur + 1;
        nxt = (nxt == 2) ? 0 : nxt + 1;
    }

    #pragma unroll
    for (int mt = 0; mt < 2; ++mt) {
        const int mbase = m0blk + wm * 64 + mt * 32 + 4 * lk;
        #pragma unroll
        for (int nt = 0; nt < 2; ++nt) {
            const int n = n0blk + wn * 64 + nt * 32 + lr;
            const float ws = wscale_p[n >> ws_shift];
            v16i a = acc[mt][nt];
            #pragma unroll
            for (int r = 0; r < 16; ++r) {
                int m = mbase + (r & 3) + 8 * (r >> 2);
                float sc = ws * ascale[m] / 127.0f;
                float v = (float)a[r] * sc;
                size_t oi = (size_t)m * N + n;
                if (mode == 3) {
                    ((_Float16*)out)[oi] = (_Float16)v;   // fp16 QKV store
                } else {
                    if (mode == 1) v += aux[oi];
                    else if (mode == 2) v = v / (1.0f + expf(-v)) * aux[oi];
                    out[oi] = v;
                }
            }
        }
    }
}

// ---------------- split-K int8 GEMM for wd (raw i32 partials) --------------
// Grid (16,16,4): 1024 blocks -> 3 blocks/CU (vs 256 = 1/CU single-pass).
// i32 partial sums are exact; wd_reduce adds them (associative) -> result is
// bit-identical to the single-pass accumulation. Swizzle: cw=16, ch=8 ->
// each XCD owns half a z-slice (8 A-slices + 16 B-slices ~ 6 MB footprint).
__global__ __launch_bounds__(256, 3) void gemm_mfma_splitk(
        const int8_t* __restrict__ Aq, const int8_t* __restrict__ Wq,
        int* __restrict__ pout, int nkt_total, int nkt_slice) {
    __shared__ int8_t As[3][8192];
    __shared__ int8_t Bs[3][8192];
    const int tid = threadIdx.x;
    const int w = tid >> 6;
    const int l = tid & 63;
    const int wm = w & 1, wn = w >> 1;
    const int lk = l >> 5, lr = l & 31;

    const int gy = gridDim.y, gx = gridDim.x;
    int id = ((int)blockIdx.z * gy + (int)blockIdx.y) * gx + (int)blockIdx.x;
    int c = id & 7, jj = id >> 3;          // jj in [0,128)
    int z  = c >> 1;
    int by = (c & 1) * 8 + (jj >> 4);
    int bx = jj & 15;

    const int8_t* ag = Aq + ((size_t)by * nkt_total + z * nkt_slice) * 8192
                     + w * 2048 + l * 16;
    const int8_t* bg = Wq + ((size_t)bx * nkt_total + z * nkt_slice) * 8192
                     + w * 2048 + l * 16;
    const int lo = w * 2048;

    const int aoff = (lk * 128 + wm * 64 + lr) * 16;
    const int boff = (lk * 128 + wn * 64 + lr) * 16;

    v16i acc[2][2] = {};

    auto stage = [&](int kt, int b) {
        const int8_t* a = ag + (size_t)kt * 8192;
        const int8_t* bs = bg + (size_t)kt * 8192;
        gll16(a,         As[b] + lo);
        gll16(a + 1024,  As[b] + lo + 1024);
        gll16(bs,        Bs[b] + lo);
        gll16(bs + 1024, Bs[b] + lo + 1024);
    };

    stage(0, 0);
    stage(1, 1);
    int cur = 0, nxt = 2;
    for (int kt = 0; kt < nkt_slice; ++kt) {
        if (kt + 2 < nkt_slice) {
            stage(kt + 2, nxt);
            asm volatile("s_waitcnt vmcnt(8)" ::: "memory");
        } else if (kt + 1 < nkt_slice) {
            asm volatile("s_waitcnt vmcnt(4)" ::: "memory");
        } else {
            asm volatile("s_waitcnt vmcnt(0)" ::: "memory");
        }
        __builtin_amdgcn_s_barrier();
        #pragma unroll
        for (int ks = 0; ks < 2; ++ks) {
            v4i a0 = *(const v4i*)(As[cur] + aoff + ks * 4096);
            v4i a1 = *(const v4i*)(As[cur] + aoff + ks * 4096 + 512);
            v4i b0 = *(const v4i*)(Bs[cur] + boff + ks * 4096);
            v4i b1 = *(const v4i*)(Bs[cur] + boff + ks * 4096 + 512);
            acc[0][0] = __builtin_amdgcn_mfma_i32_32x32x32_i8(a0, b0, acc[0][0], 0, 0, 0);
            acc[0][1] = __builtin_amdgcn_mfma_i32_32x32x32_i8(a0, b1, acc[0][1], 0, 0, 0);
            acc[1][0] = __builtin_amdgcn_mfma_i32_32x32x32_i8(a1, b0, acc[1][0], 0, 0, 0);
            acc[1][1] = __builtin_amdgcn_mfma_i32_32x32x32_i8(a1, b1, acc[1][1], 0, 0, 0);
        }
        asm volatile("s_waitcnt lgkmcnt(0)" ::: "memory");
        __builtin_amdgcn_s_barrier();
        cur = (cur == 2) ? 0 : cur + 1;
        nxt = (nxt == 2) ? 0 : nxt + 1;
    }

    int* pb = pout + (size_t)z * T_DIM * D_DIM;
    #pragma unroll
    for (int mt = 0; mt < 2; ++mt) {
        const int mbase = by * 128 + wm * 64 + mt * 32 + 4 * lk;
        #pragma unroll
        for (int nt = 0; nt < 2; ++nt) {
            const int n = bx * 128 + wn * 64 + nt * 32 + lr;
            v16i a = acc[mt][nt];
            #pragma unroll
            for (int r = 0; r < 16; ++r) {
                int m = mbase + (r & 3) + 8 * (r >> 2);
                pb[(size_t)m * D_DIM + n] = a[r];
            }
        }
    }
}

// ---------------- wd split-K reduction + scale + residual ------------------
__global__ void wd_reduce(const int* __restrict__ pb, const float* __restrict__ ascale,
                          const float* __restrict__ wsc6, const float* __restrict__ aux,
                          float* __restrict__ out) {
    const int m = blockIdx.x;
    const float sc = (*wsc6) * ascale[m] / 127.0f;
    const size_t zs = (size_t)T_DIM * D_DIM / 4;   // z-stride in v4i units
    const v4i* p0 = (const v4i*)pb + (size_t)m * (D_DIM / 4);
    const float4* auxr = (const float4*)(aux + (size_t)m * D_DIM);
    float4* outr = (float4*)(out + (size_t)m * D_DIM);
    for (int i = threadIdx.x; i < D_DIM / 4; i += 256) {
        v4i s0 = p0[i], s1 = p0[i + zs], s2 = p0[i + 2 * zs], s3 = p0[i + 3 * zs];
        float4 a = auxr[i];
        float4 o;
        o.x = (float)(s0.x + s1.x + s2.x + s3.x) * sc + a.x;
        o.y = (float)(s0.y + s1.y + s2.y + s3.y) * sc + a.y;
        o.z = (float)(s0.z + s1.z + s2.z + s3.z) * sc + a.z;
        o.w = (float)(s0.w + s1.w + s2.w + s3.w) * sc + a.w;
        outr[i] = o;
    }
}

// ---------------- fused MLP up+gate GEMM (silu(x@wg^T)*(x@wu^T)) -----------
__global__ __launch_bounds__(256, 2) void gemm_mlp_fused(
        const int8_t* __restrict__ Aq, const int8_t* __restrict__ Wg,
        const int8_t* __restrict__ Wu, float* __restrict__ out,
        const float* __restrict__ ascale, const float* __restrict__ wsc_g,
        const float* __restrict__ wsc_u, int cw, int ch) {
    __shared__ int8_t As[3][8192];
    __shared__ int8_t Gs[3][8192];
    __shared__ int8_t Us[3][8192];
    const int tid = threadIdx.x;
    const int w = tid >> 6;
    const int l = tid & 63;
    const int wm = w & 1, wn = w >> 1;
    const int lk = l >> 5, lr = l & 31;
    const int K = D_DIM;
    const int nkt = K >> 6;   // 32

    const int gx = gridDim.x;
    const int ncx = gx / cw;
    int id = (int)blockIdx.y * gx + (int)blockIdx.x;
    int c = id & 7, j = id >> 3;
    int by = (c / ncx) * ch + j / cw;
    int bx = (c % ncx) * cw + j % cw;
    const int m0blk = by * 128;
    const int n0blk = bx * 128;

    const int8_t* ag = Aq + ((size_t)by * nkt) * 8192 + w * 2048 + l * 16;
    const int8_t* gg = Wg + ((size_t)bx * nkt) * 8192 + w * 2048 + l * 16;
    const int8_t* ug = Wu + ((size_t)bx * nkt) * 8192 + w * 2048 + l * 16;
    const int lo = w * 2048;

    const int aoff = (lk * 128 + wm * 64 + lr) * 16;
    const int boff = (lk * 128 + wn * 64 + lr) * 16;

    v16i accg[2][2] = {};
    v16i accu[2][2] = {};

    auto stage = [&](int kt, int b) {
        const int8_t* a = ag + (size_t)kt * 8192;
        const int8_t* g = gg + (size_t)kt * 8192;
        const int8_t* u = ug + (size_t)kt * 8192;
        gll16(a,        As[b] + lo);
        gll16(a + 1024, As[b] + lo + 1024);
        gll16(g,        Gs[b] + lo);
        gll16(g + 1024, Gs[b] + lo + 1024);
        gll16(u,        Us[b] + lo);
        gll16(u + 1024, Us[b] + lo + 1024);
    };

    stage(0, 0);
    stage(1, 1);
    int cur = 0, nxt = 2;
    for (int kt = 0; kt < nkt; ++kt) {
        if (kt + 2 < nkt) {
            stage(kt + 2, nxt);
            asm volatile("s_waitcnt vmcnt(12)" ::: "memory");
        } else if (kt + 1 < nkt) {
            asm volatile("s_waitcnt vmcnt(6)" ::: "memory");
        } else {
            asm volatile("s_waitcnt vmcnt(0)" ::: "memory");
        }
        __builtin_amdgcn_s_barrier();
        #pragma unroll
        for (int ks = 0; ks < 2; ++ks) {
            v4i a0 = *(const v4i*)(As[cur] + aoff + ks * 4096);
            v4i a1 = *(const v4i*)(As[cur] + aoff + ks * 4096 + 512);
            v4i g0 = *(const v4i*)(Gs[cur] + boff + ks * 4096);
            v4i g1 = *(const v4i*)(Gs[cur] + boff + ks * 4096 + 512);
            v4i u0 = *(const v4i*)(Us[cur] + boff + ks * 4096);
            v4i u1 = *(const v4i*)(Us[cur] + boff + ks * 4096 + 512);
            accg[0][0] = __builtin_amdgcn_mfma_i32_32x32x32_i8(a0, g0, accg[0][0], 0, 0, 0);
            accg[0][1] = __builtin_amdgcn_mfma_i32_32x32x32_i8(a0, g1, accg[0][1], 0, 0, 0);
            accg[1][0] = __builtin_amdgcn_mfma_i32_32x32x32_i8(a1, g0, accg[1][0], 0, 0, 0);
            accg[1][1] = __builtin_amdgcn_mfma_i32_32x32x32_i8(a1, g1, accg[1][1], 0, 0, 0);
            accu[0][0] = __builtin_amdgcn_mfma_i32_32x32x32_i8(a0, u0, accu[0][0], 0, 0, 0);
            accu[0][1] = __builtin_amdgcn_mfma_i32_32x32x32_i8(a0, u1, accu[0][1], 0, 0, 0);
            accu[1][0] = __builtin_amdgcn_mfma_i32_32x32x32_i8(a1, u0, accu[1][0], 0, 0, 0);
            accu[1][1] = __builtin_amdgcn_mfma_i32_32x32x32_i8(a1, u1, accu[1][1], 0, 0, 0);
        }
        asm volatile("s_waitcnt lgkmcnt(0)" ::: "memory");
        __builtin_amdgcn_s_barrier();
        cur = (cur == 2) ? 0 : cur + 1;
        nxt = (nxt == 2) ? 0 : nxt + 1;
    }

    const float wsg = *wsc_g;
    const float wsu = *wsc_u;
    #pragma unroll
    for (int mt = 0; mt < 2; ++mt) {
        const int mbase = m0blk + wm * 64 + mt * 32 + 4 * lk;
        #pragma unroll
        for (int nt = 0; nt < 2; ++nt) {
            const int n = n0blk + wn * 64 + nt * 32 + lr;
            v16i g = accg[mt][nt];
            v16i u = accu[mt][nt];
            #pragma unroll
            for (int r = 0; r < 16; ++r) {
                int m = mbase + (r & 3) + 8 * (r >> 2);
                float sc = ascale[m] / 127.0f;
                float gv = (float)g[r] * (wsg * sc);
                float uv = (float)u[r] * (wsu * sc);
                float v = gv / (1.0f + expf(-gv)) * uv;
                out[(size_t)m * MLP_DIM + n] = v;
            }
        }
    }
}

// ---------------- fp16 MFMA flash attention (4-wave key-split) -------------
__global__ __launch_bounds__(256) void attn_mfma(const _Float16* __restrict__ QKV,
                                                 float* __restrict__ O) {
    __shared__ __align__(16) char LDS[73728];  // 4 waves * (8K K + 8K Vt + 2K P)
    const int tid  = threadIdx.x;
    const int wk   = tid >> 6;          // wave id = key phase 0..3
    const int l    = tid & 63;
    const int half = l >> 5;
    const int lr   = l & 31;
    const int qt   = (int)gridDim.x - 1 - (int)blockIdx.x;  // big tiles first
    const int bh   = blockIdx.y;
    const int b = bh >> 4, h = bh & 15;
    const int tok0 = b * S_DIM;
    const float scale = 0.08838834764831845f;  // 1/sqrt(128)

    char* myK = LDS + wk * 18432;
    char* myV = myK + 8192;
    char* myP = myK + 16384;

    v8h qa[8];
    {
        const _Float16* qrow = QKV + (size_t)(tok0 + qt * 32 + lr) * LDQ + h * HD_DIM;
        #pragma unroll
        for (int s = 0; s < 8; ++s)
            qa[s] = *(const v8h*)(qrow + s * 16 + half * 8);
    }
    v8h ones;
    #pragma unroll
    for (int j = 0; j < 8; ++j) ones[j] = (_Float16)1.0f;

    v16f oacc[4] = {zero16(), zero16(), zero16(), zero16()};
    v16f lacc = zero16();

    for (int kt = wk; kt <= qt; kt += 4) {
        const int kt0 = tok0 + kt * 32;

        v8h va[4], vb[4];
        #pragma unroll
        for (int it = 0; it < 4; ++it) {
            int unit = it * 64 + l;
            int kp = unit & 15, g = unit >> 4;
            const _Float16* s0 = QKV + (size_t)(kt0 + 2 * kp) * LDQ + 2 * D_DIM
                                 + h * HD_DIM + g * 8;
            va[it] = *(const v8h*)s0;
            vb[it] = *(const v8h*)(s0 + LDQ);
        }
        #pragma unroll
        for (int it = 0; it < 8; ++it) {
            int unit = it * 64 + l;
            int key = unit >> 4, gs = unit & 15;
            int g = gs ^ (key & 15);
            gll16(QKV + (size_t)(kt0 + key) * LDQ + D_DIM + h * HD_DIM + g * 8,
                  myK + it * 1024);
        }
        #pragma unroll
        for (int it = 0; it < 4; ++it) {
            int unit = it * 64 + l;
            int kp = unit & 15, g = unit >> 4;
            int kg = kp >> 2, ko = (kp & 3) * 4;
            #pragma unroll
            for (int j = 0; j < 8; ++j) {
                int d = g * 8 + j;
                union { _Float16 hh[2]; unsigned u; } pk;
                pk.hh[0] = va[it][j];
                pk.hh[1] = vb[it][j];
                *(unsigned*)(myV + d * 64 + ((kg ^ (d & 3)) * 16) + ko) = pk.u;
            }
        }
        asm volatile("s_waitcnt vmcnt(0)" ::: "memory");

        v16f sacc = zero16();
        #pragma unroll
        for (int s = 0; s < 8; ++s) {
            int gi = half + 2 * s;
            v8h kb = *(const v8h*)(myK + lr * 256 + ((gi ^ (lr & 15)) * 16));
            sacc = __builtin_amdgcn_mfma_f32_32x32x16_f16(qa[s], kb, sacc, 0, 0, 0);
        }

        const bool diag = (kt == qt);
        #pragma unroll
        for (int r = 0; r < 16; ++r) {
            int row = (r & 3) + 8 * (r >> 2) + 4 * half;   // q offset
            float p = (!diag || lr <= row) ? __expf(sacc[r] * scale) : 0.0f;
            int kg2 = lr >> 3;
            *(_Float16*)(myP + row * 64 + ((kg2 ^ (row & 3)) * 16) + (lr & 7) * 2) = (_Float16)p;
        }

        #pragma unroll
        for (int s2 = 0; s2 < 2; ++s2) {
            int pg = half + 2 * s2;
            v8h pa = *(const v8h*)(myP + lr * 64 + ((pg ^ (lr & 3)) * 16));
            lacc = __builtin_amdgcn_mfma_f32_32x32x16_f16(pa, ones, lacc, 0, 0, 0);
            #pragma unroll
            for (int nt = 0; nt < 4; ++nt) {
                int d = nt * 32 + lr;
                int kgv = half + 2 * s2;
                v8h vbf = *(const v8h*)(myV + d * 64 + ((kgv ^ (d & 3)) * 16));
                oacc[nt] = __builtin_amdgcn_mfma_f32_32x32x16_f16(pa, vbf, oacc[nt], 0, 0, 0);
            }
        }
    }

    __syncthreads();
    float* red = (float*)LDS;
    if (wk > 0) {
        float* reg = red + (size_t)(wk - 1) * 5120;   // 20 KB per region
        #pragma unroll
        for (int r = 0; r < 16; ++r) {
            int slot = half * 16 + r;
            #pragma unroll
            for (int nt = 0; nt < 4; ++nt)
                reg[(slot * 5 + nt) * 32 + lr] = oacc[nt][r];
            reg[(slot * 5 + 4) * 32 + lr] = lacc[r];
        }
    }
    __syncthreads();
    if (wk == 0) {
        #pragma unroll
        for (int w = 0; w < 3; ++w) {
            float* reg = red + (size_t)w * 5120;
            #pragma unroll
            for (int r = 0; r < 16; ++r) {
                int slot = half * 16 + r;
                #pragma unroll
                for (int nt = 0; nt < 4; ++nt)
                    oacc[nt][r] += reg[(slot * 5 + nt) * 32 + lr];
                lacc[r] += reg[(slot * 5 + 4) * 32 + lr];
            }
        }
        #pragma unroll
        for (int nt = 0; nt < 4; ++nt) {
            #pragma unroll
            for (int r = 0; r < 16; ++r) {
                int row = (r & 3) + 8 * (r >> 2) + 4 * half;
                O[(size_t)(tok0 + qt * 32 + row) * D_DIM + h * HD_DIM + nt * 32 + lr] =
                    oacc[nt][r] / lacc[r];
            }
        }
    }
}

extern "C" void kernel_launch(void* const* d_in, const int* in_sizes, int n_in,
                              void* d_out, int out_size, void* d_ws, size_t ws_size,
                              hipStream_t stream) {
    const float* x  = (const float*)d_in[0];
    const float* n1 = (const float*)d_in[8];
    const float* n2 = (const float*)d_in[9];
    float* out = (float*)d_out;

    // ---- workspace arena ----
    uint8_t* base = (uint8_t*)d_ws;
    size_t o = 0;
    auto alloc = [&](size_t bytes) -> uint8_t* {
        o = (o + 255) & ~(size_t)255;
        uint8_t* p = base + o;
        o += bytes;
        return p;
    };
    const size_t DD = (size_t)D_DIM * D_DIM;
    const size_t MD = (size_t)MLP_DIM * D_DIM;
    const size_t TD = (size_t)T_DIM * D_DIM;
    const size_t TM = (size_t)T_DIM * MLP_DIM;

    int8_t* wqkvQ = (int8_t*)alloc(3 * DD);   // q,k,v contiguous for fused GEMM
    int8_t* woQ   = (int8_t*)alloc(DD);
    int8_t* wgQ   = (int8_t*)alloc(MD);
    int8_t* wuQ   = (int8_t*)alloc(MD);
    int8_t* wdQ   = (int8_t*)alloc(MD);
    float*  wsc   = (float*)alloc(8 * sizeof(float));
    float*  part  = (float*)alloc(7 * 1024 * sizeof(float));
    float*  asc   = (float*)alloc(T_DIM * sizeof(float));
    int8_t* actQ  = (int8_t*)alloc(TM);
    float*  F     = (float*)alloc(5 * TD * sizeof(float));
    float* QKVf = F;            // [T, 6144] as fp16 (uses half the region)
    float* AOf  = F + 3 * TD;
    float* x2f  = F + 4 * TD;
    float* yuf  = F;            // aliases QKV+AOf (4*TD floats); dead by then
    int*   wdP  = (int*)F;      // wd split-K partials: 4 x TD i32 = F[0..4TD)
                                // (QKV/AO dead by wd time; x2f at 4TD is safe)

    // ---- fused weight quantization: 3 launches for all 7 weights ----
    WPack p;
    p.w[0] = (const float4*)d_in[1];  p.q[0] = (char4*)wqkvQ;            p.n4[0] = (int)(DD >> 2);
    p.w[1] = (const float4*)d_in[2];  p.q[1] = (char4*)(wqkvQ + DD);     p.n4[1] = (int)(DD >> 2);
    p.w[2] = (const float4*)d_in[3];  p.q[2] = (char4*)(wqkvQ + 2 * DD); p.n4[2] = (int)(DD >> 2);
    p.w[3] = (const float4*)d_in[4];  p.q[3] = (char4*)woQ;              p.n4[3] = (int)(DD >> 2);
    p.w[4] = (const float4*)d_in[5];  p.q[4] = (char4*)wgQ;              p.n4[4] = (int)(MD >> 2);
    p.w[5] = (const float4*)d_in[6];  p.q[5] = (char4*)wuQ;              p.n4[5] = (int)(MD >> 2);
    p.w[6] = (const float4*)d_in[7];  p.q[6] = (char4*)wdQ;              p.n4[6] = (int)(MD >> 2);
    p.ksh[0] = p.ksh[1] = p.ksh[2] = p.ksh[3] = p.ksh[4] = p.ksh[5] = 9;
    p.ksh[6] = 11;
    wabs_partial_all<<<dim3(1024, 7), 256, 0, stream>>>(p, part);
    wabs_final_all<<<7, 256, 0, stream>>>(part, p, wsc);
    quant_w_all<<<dim3(2048, 7), 256, 0, stream>>>(p, wsc);

    // ---- attention half ----
    rmsnorm_quant<<<T_DIM, 256, 0, stream>>>(x, n1, actQ, asc, D_DIM);
    dim3 gqkv(3 * D_DIM / 128, T_DIM / 128);           // 48 x 16
    gemm_mfma<<<gqkv, 256, 0, stream>>>(actQ, wqkvQ, QKVf, asc, wsc + 0, nullptr,
                                        3 * D_DIM, D_DIM, 3, 11, 12, 8);
    dim3 ga(S_DIM / 32, B_DIM * H_DIM);
    attn_mfma<<<ga, 256, 0, stream>>>((const _Float16*)QKVf, AOf);
    act_quant<<<T_DIM, 256, 0, stream>>>(AOf, actQ, asc, D_DIM);
    dim3 g1(D_DIM / 128, T_DIM / 128);                 // 16 x 16
    gemm_mfma<<<g1, 256, 0, stream>>>(actQ, woQ, x2f, asc, wsc + 3, x,
                                      D_DIM, D_DIM, 1, 30, 8, 4);

    // ---- MLP half ----
    rmsnorm_quant<<<T_DIM, 256, 0, stream>>>(x2f, n2, actQ, asc, D_DIM);
    dim3 g2(MLP_DIM / 128, T_DIM / 128);               // 64 x 16
    gemm_mlp_fused<<<g2, 256, 0, stream>>>(actQ, wgQ, wuQ, yuf, asc,
                                           wsc + 4, wsc + 5, 8, 16);
    act_quant<<<T_DIM, 256, 0, stream>>>(yuf, actQ, asc, MLP_DIM);
    dim3 gwd(D_DIM / 128, T_DIM / 128, 4);             // 16 x 16 x 4 split-K
    gemm_mfma_splitk<<<gwd, 256, 0, stream>>>(actQ, wdQ, wdP,
                                              MLP_DIM / 64, MLP_DIM / 64 / 4);
    wd_reduce<<<T_DIM, 256, 0, stream>>>(wdP, asc, wsc + 6, x2f, out);
}